// Round 9
// baseline (994.883 us; speedup 1.0000x reference)
//
#include <hip/hip_runtime.h>
#include <stdint.h>

#define N_TOT 100000
#define IN_CHN 1024
#define MDIM 512
#define ATT_D 128
#define NUM_GROUP 8
#define GROUP_SIZE 12500
#define LDST 72  // padded LDS row stride in shorts (kattn only)
#define SEGR 98  // rows per kbag segment

typedef __bf16 bf16x8 __attribute__((ext_vector_type(8)));
typedef float f32x4 __attribute__((ext_vector_type(4)));
typedef unsigned short u16x8 __attribute__((ext_vector_type(8)));

__device__ __forceinline__ unsigned short f2bf(float x){
  union { float f; unsigned u; } v; v.f = x;
  unsigned r = v.u + 0x7fffu + ((v.u >> 16) & 1u);
  return (unsigned short)(r >> 16);
}
__device__ __forceinline__ float bf2f(unsigned short h){
  union { unsigned u; float f; } v; v.u = ((unsigned)h) << 16; return v.f;
}
__device__ __forceinline__ void gload16(const void* g, void* l){
  __builtin_amdgcn_global_load_lds(
      (const __attribute__((address_space(1))) unsigned int*)g,
      (__attribute__((address_space(3))) unsigned int*)l, 16, 0, 0);
}

// ---------------- weight conversion f32 -> bf16 ----------------
__global__ __launch_bounds__(256) void kconv(const float* __restrict__ W1,
                                             const float* __restrict__ Wa1,
                                             unsigned short* __restrict__ W1b,
                                             unsigned short* __restrict__ Wa1b){
  int i = blockIdx.x * 256 + threadIdx.x;
  if (i < MDIM * IN_CHN) W1b[i] = f2bf(W1[i]);
  else {
    int j = i - MDIM * IN_CHN;
    if (j < ATT_D * MDIM) Wa1b[j] = f2bf(Wa1[j]);
  }
}

// ---------------- main gather + GEMM: mid = relu(tfeat[idx] @ W1^T + b1) ----------------
// 128x128 tile, BK=64. A: global->reg->cvt->MFMA (no LDS). B: global_load_lds,
// linear [128][64] bf16, double-buffered, 1 barrier/step. XCD swizzle.
__global__ __launch_bounds__(256) void kgemm_mid(const int* __restrict__ idxf,
                                                 const float* __restrict__ tfeat,
                                                 const unsigned short* __restrict__ W1b,
                                                 const float* __restrict__ b1,
                                                 unsigned short* __restrict__ midb){
  __shared__ alignas(16) unsigned short Bsm[2][128 * 64];
  __shared__ int gsm[128];
  int tid = threadIdx.x;
  int bid = blockIdx.x;
  int tile = (bid & 7) * 391 + (bid >> 3);   // XCD-aware: bn-siblings adjacent on one XCD
  int bn = tile & 3, bm = tile >> 2;
  int m0 = bm * 128, n0 = bn * 128;
  if (tid < 128){ int r = m0 + tid; gsm[tid] = idxf[r < N_TOT ? r : 0]; }
  __syncthreads();

  int w = tid >> 6, l = tid & 63;
  int l16 = tid & 15, hi = (tid >> 4) & 3;
  int wm = tid >> 7, wn = (tid >> 6) & 1;

  // B staging sources (per-lane global addr; LDS dest wave-uniform base + lane*16)
  const unsigned short* bsrc[4];
  int bdst[4];
  #pragma unroll
  for (int q = 0; q < 4; q++){
    int row = q * 32 + w * 8 + (l >> 3);
    bsrc[q] = W1b + (size_t)(n0 + row) * IN_CHN + (l & 7) * 8;
    bdst[q] = (q * 32 + w * 8) * 64;
  }
  // A fragment row pointers (per-lane, direct from gathered tfeat)
  const float* aptr[4];
  #pragma unroll
  for (int a = 0; a < 4; a++)
    aptr[a] = tfeat + (size_t)gsm[wm * 64 + a * 16 + l16] * IN_CHN + hi * 8;

  f32x4 acc[4][4];
  #pragma unroll
  for (int a = 0; a < 4; a++)
    #pragma unroll
    for (int b = 0; b < 4; b++) acc[a][b] = (f32x4){0.f, 0.f, 0.f, 0.f};

  auto stageB = [&](int s, int buf){
    #pragma unroll
    for (int q = 0; q < 4; q++)
      gload16(bsrc[q] + s * 64, &Bsm[buf][bdst[q]]);
  };

  stageB(0, 0);
  __syncthreads();   // drains DMA (implicit vmcnt(0))

  for (int s = 0; s < 16; s++){
    int cur = s & 1;
    if (s + 1 < 16) stageB(s + 1, cur ^ 1);   // DMA overlaps compute
    #pragma unroll
    for (int ks = 0; ks < 2; ks++){
      bf16x8 af[4];
      #pragma unroll
      for (int a = 0; a < 4; a++){
        const float4* p = (const float4*)(aptr[a] + s * 64 + ks * 32);
        float4 x = p[0], y = p[1];
        bf16x8 pk;
        pk[0] = (__bf16)x.x; pk[1] = (__bf16)x.y; pk[2] = (__bf16)x.z; pk[3] = (__bf16)x.w;
        pk[4] = (__bf16)y.x; pk[5] = (__bf16)y.y; pk[6] = (__bf16)y.z; pk[7] = (__bf16)y.w;
        af[a] = pk;
      }
      bf16x8 bfr[4];
      #pragma unroll
      for (int b = 0; b < 4; b++)
        bfr[b] = *(const bf16x8*)&Bsm[cur][(wn * 64 + b * 16 + l16) * 64 + (ks * 4 + hi) * 8];
      #pragma unroll
      for (int a = 0; a < 4; a++)
        #pragma unroll
        for (int b = 0; b < 4; b++)
          acc[a][b] = __builtin_amdgcn_mfma_f32_16x16x32_bf16(af[a], bfr[b], acc[a][b], 0, 0, 0);
    }
    __syncthreads();  // next buf ready; everyone done with cur
  }

  #pragma unroll
  for (int b = 0; b < 4; b++){
    int col = n0 + wn * 64 + b * 16 + l16;
    float bias = b1[col];
    #pragma unroll
    for (int a = 0; a < 4; a++){
      int rbase = m0 + wm * 64 + a * 16 + hi * 4;
      #pragma unroll
      for (int q = 0; q < 4; q++){
        int row = rbase + q;
        if (row < N_TOT){
          float v = acc[a][b][q] + bias;
          midb[(size_t)row * MDIM + col] = f2bf(fmaxf(v, 0.f));
        }
      }
    }
  }
}

// ---------------- attention MLP + fused tv ----------------
__global__ __launch_bounds__(256) void kattn(const unsigned short* __restrict__ midb,
                                             const unsigned short* __restrict__ Wa1b,
                                             const float* __restrict__ ba1,
                                             const float* __restrict__ Wa2,
                                             const float* __restrict__ ba2,
                                             const float* __restrict__ Wc,
                                             float* __restrict__ lv,
                                             float* __restrict__ tv){
  __shared__ alignas(16) unsigned short Asm[128 * LDST];
  __shared__ alignas(16) unsigned short Bsm[128 * LDST];
  __shared__ float dsh[512];
  __shared__ float part[128][2];
  int tid = threadIdx.x;
  int m0 = blockIdx.x * 128;
  for (int i = tid; i < 512; i += 256) dsh[i] = Wc[512 + i] - Wc[i];

  int lane8 = tid & 7, rq = tid >> 3;
  const unsigned short *asrc[4], *bsrc[4];
  unsigned short *adst[4], *bdst[4];
  #pragma unroll
  for (int p = 0; p < 4; p++){
    int r = p * 32 + rq;
    int rowc = m0 + r; if (rowc > N_TOT - 1) rowc = N_TOT - 1;
    asrc[p] = midb + (size_t)rowc * MDIM + lane8 * 8;
    bsrc[p] = Wa1b + (size_t)r * MDIM + lane8 * 8;
    adst[p] = &Asm[r * LDST + lane8 * 8];
    bdst[p] = &Bsm[r * LDST + lane8 * 8];
  }
  int l16 = tid & 15, hi = (tid >> 4) & 3;
  int wm = tid >> 7, wn = (tid >> 6) & 1;
  f32x4 acc[4][4];
  #pragma unroll
  for (int a = 0; a < 4; a++)
    #pragma unroll
    for (int b = 0; b < 4; b++) acc[a][b] = (f32x4){0.f, 0.f, 0.f, 0.f};
  float tpart[4] = {0.f, 0.f, 0.f, 0.f};

  for (int s = 0; s < 8; s++){
    __syncthreads();
    #pragma unroll
    for (int p = 0; p < 4; p++){
      u16x8 av = *(const u16x8*)(asrc[p] + s * 64);
      *(u16x8*)adst[p] = av;
      *(u16x8*)bdst[p] = *(const u16x8*)(bsrc[p] + s * 64);
      #pragma unroll
      for (int e = 0; e < 8; e++)
        tpart[p] += bf2f((unsigned short)av[e]) * dsh[s * 64 + lane8 * 8 + e];
    }
    __syncthreads();
    #pragma unroll
    for (int ks = 0; ks < 2; ks++){
      int off = (ks * 4 + hi) * 8;
      bf16x8 af[4], bfr[4];
      #pragma unroll
      for (int a = 0; a < 4; a++){ int row = wm * 64 + a * 16 + l16; af[a] = *(const bf16x8*)&Asm[row * LDST + off]; }
      #pragma unroll
      for (int b = 0; b < 4; b++){ int col = wn * 64 + b * 16 + l16; bfr[b] = *(const bf16x8*)&Bsm[col * LDST + off]; }
      #pragma unroll
      for (int a = 0; a < 4; a++)
        #pragma unroll
        for (int b = 0; b < 4; b++)
          acc[a][b] = __builtin_amdgcn_mfma_f32_16x16x32_bf16(af[a], bfr[b], acc[a][b], 0, 0, 0);
    }
  }
  #pragma unroll
  for (int p = 0; p < 4; p++){
    float t = tpart[p];
    t += __shfl_xor(t, 1); t += __shfl_xor(t, 2); t += __shfl_xor(t, 4);
    if (lane8 == 0){
      int row = m0 + p * 32 + rq;
      if (row < N_TOT) tv[row] = t;
    }
  }
  #pragma unroll
  for (int a = 0; a < 4; a++){
    #pragma unroll
    for (int q = 0; q < 4; q++){
      float v = 0.f;
      #pragma unroll
      for (int b = 0; b < 4; b++){
        int col = wn * 64 + b * 16 + l16;
        v += tanhf(acc[a][b][q] + ba1[col]) * Wa2[col];
      }
      #pragma unroll
      for (int off = 1; off < 16; off <<= 1) v += __shfl_xor(v, off);
      if (l16 == 0) part[wm * 64 + a * 16 + hi * 4 + q][wn] = v;
    }
  }
  __syncthreads();
  if (tid < 128){
    int row = m0 + tid;
    if (row < N_TOT) lv[row] = part[tid][0] + part[tid][1] + ba2[0];
  }
}

// ---------------- per-group stats + top/bottom-16 + fused softmax weights ----------------
__global__ __launch_bounds__(256) void kselect(const float* __restrict__ lv,
                                               const float* __restrict__ tv,
                                               float* __restrict__ maxlw, float* __restrict__ Zw,
                                               int* __restrict__ cand,
                                               float* __restrict__ w){
  __shared__ float keys[GROUP_SIZE];
  __shared__ unsigned char flg[GROUP_SIZE];
  __shared__ float rk[256];
  __shared__ int ri[256];
  __shared__ float sbc;
  int g = blockIdx.x, tid = threadIdx.x;
  const float* lg = lv + (size_t)g * GROUP_SIZE;
  const float* tg = tv + (size_t)g * GROUP_SIZE;

  float mx = -1e30f;
  for (int i = tid; i < GROUP_SIZE; i += 256) mx = fmaxf(mx, lg[i]);
  rk[tid] = mx; __syncthreads();
  for (int s = 128; s > 0; s >>= 1){ if (tid < s) rk[tid] = fmaxf(rk[tid], rk[tid + s]); __syncthreads(); }
  if (tid == 0) sbc = rk[0];
  __syncthreads();
  float maxl = sbc;

  float z = 0.f;
  for (int i = tid; i < GROUP_SIZE; i += 256){
    float ez = expf(lg[i] - maxl);
    z += ez;
    keys[i] = ez * tg[i];
    flg[i] = 0;
  }
  rk[tid] = z; __syncthreads();
  for (int s = 128; s > 0; s >>= 1){ if (tid < s) rk[tid] += rk[tid + s]; __syncthreads(); }
  if (tid == 0){ maxlw[g] = maxl; Zw[g] = rk[0]; }
  __syncthreads();
  float invZ = 1.0f / rk[0];
  for (int i = tid; i < GROUP_SIZE; i += 256)
    w[(size_t)g * GROUP_SIZE + i] = expf(lg[i] - maxl) * invZ;

  for (int it = 0; it < 16; it++){
    float bk = -1e30f; int bi = -1;
    for (int i = tid; i < GROUP_SIZE; i += 256)
      if (!flg[i]){ float k = keys[i]; if (k > bk || (k == bk && (unsigned)i < (unsigned)bi)){ bk = k; bi = i; } }
    rk[tid] = bk; ri[tid] = bi; __syncthreads();
    for (int s = 128; s > 0; s >>= 1){
      if (tid < s){
        if (rk[tid + s] > rk[tid] || (rk[tid + s] == rk[tid] && (unsigned)ri[tid + s] < (unsigned)ri[tid])){
          rk[tid] = rk[tid + s]; ri[tid] = ri[tid + s];
        }
      }
      __syncthreads();
    }
    if (tid == 0){ cand[g * 32 + it] = ri[0]; flg[ri[0]] = 1; }
    __syncthreads();
  }
  for (int it = 0; it < 16; it++){
    float bk = 1e30f; int bi = -1;
    for (int i = tid; i < GROUP_SIZE; i += 256)
      if (!flg[i]){ float k = keys[i]; if (k < bk || (k == bk && i > bi)){ bk = k; bi = i; } }
    rk[tid] = bk; ri[tid] = bi; __syncthreads();
    for (int s = 128; s > 0; s >>= 1){
      if (tid < s){
        if (rk[tid + s] < rk[tid] || (rk[tid + s] == rk[tid] && ri[tid + s] > ri[tid])){
          rk[tid] = rk[tid + s]; ri[tid] = ri[tid + s];
        }
      }
      __syncthreads();
    }
    if (tid == 0){ cand[g * 32 + 16 + it] = ri[0]; flg[ri[0]] = 1; }
    __syncthreads();
  }
}

// ---------------- exact f32 recompute of 256 candidate rows ----------------
__global__ __launch_bounds__(256) void kexact(const int* __restrict__ idxf,
                                              const float* __restrict__ tfeat,
                                              const float* __restrict__ W1,
                                              const float* __restrict__ b1,
                                              const float* __restrict__ Wa1,
                                              const float* __restrict__ ba1,
                                              const float* __restrict__ Wa2,
                                              const float* __restrict__ ba2,
                                              const float* __restrict__ Wc,
                                              const int* __restrict__ cand,
                                              const float* __restrict__ maxlw,
                                              float* __restrict__ emid, float* __restrict__ ekey){
  __shared__ float subs[1024];
  __shared__ float midc[512];
  __shared__ float hs[128];
  __shared__ float red[256];
  __shared__ float tsh;
  int bid = blockIdx.x; int g = bid >> 5, c = bid & 31; int tid = threadIdx.x;
  int s = cand[g * 32 + c];
  int inst = idxf[g * GROUP_SIZE + s];
  ((float4*)subs)[tid] = ((const float4*)(tfeat + (size_t)inst * IN_CHN))[tid];
  __syncthreads();

  float a0 = b1[tid], a1 = b1[tid + 256];
  const float4* w0 = (const float4*)(W1 + (size_t)tid * IN_CHN);
  const float4* w1 = (const float4*)(W1 + ((size_t)tid + 256) * IN_CHN);
  const float4* s4 = (const float4*)subs;
  #pragma unroll 4
  for (int k = 0; k < 256; k++){
    float4 sv = s4[k], wva = w0[k], wvb = w1[k];
    a0 += sv.x * wva.x + sv.y * wva.y + sv.z * wva.z + sv.w * wva.w;
    a1 += sv.x * wvb.x + sv.y * wvb.y + sv.z * wvb.z + sv.w * wvb.w;
  }
  a0 = fmaxf(a0, 0.f); a1 = fmaxf(a1, 0.f);
  midc[tid] = a0; midc[tid + 256] = a1;
  size_t eo = (size_t)(g * 32 + c) * MDIM;
  emid[eo + tid] = a0; emid[eo + tid + 256] = a1;
  __syncthreads();

  if (tid < 128){
    const float4* wr = (const float4*)(Wa1 + (size_t)tid * MDIM);
    const float4* m4 = (const float4*)midc;
    float h = ba1[tid];
    #pragma unroll 4
    for (int j = 0; j < 128; j++){
      float4 mv = m4[j], wv = wr[j];
      h += mv.x * wv.x + mv.y * wv.y + mv.z * wv.z + mv.w * wv.w;
    }
    hs[tid] = tanhf(h) * Wa2[tid];
  }
  __syncthreads();

  float tp = midc[tid] * (Wc[512 + tid] - Wc[tid]) + midc[tid + 256] * (Wc[768 + tid] - Wc[256 + tid]);
  red[tid] = tp; __syncthreads();
  for (int st = 128; st > 0; st >>= 1){ if (tid < st) red[tid] += red[tid + st]; __syncthreads(); }
  if (tid == 0) tsh = red[0];
  __syncthreads();
  red[tid] = (tid < 128) ? hs[tid] : 0.f; __syncthreads();
  for (int st = 128; st > 0; st >>= 1){ if (tid < st) red[tid] += red[tid + st]; __syncthreads(); }
  if (tid == 0){
    float lval = red[0] + ba2[0];
    ekey[g * 32 + c] = expf(lval - maxlw[g]) * tsh;
  }
}

// ---------------- weighted bag-sum: 128 segments x 8 groups, partials ----------------
__global__ __launch_bounds__(256) void kbag(const unsigned short* __restrict__ midb,
                                            const float* __restrict__ w,
                                            float* __restrict__ bagp){
  __shared__ float wl[SEGR];
  int g = blockIdx.x >> 7, seg = blockIdx.x & 127, tid = threadIdx.x;
  int i0 = seg * SEGR;
  int nr = GROUP_SIZE - i0; if (nr > SEGR) nr = SEGR;
  size_t base = (size_t)g * GROUP_SIZE;
  if (tid < nr) wl[tid] = w[base + i0 + tid];
  __syncthreads();
  float a0 = 0.f, a1 = 0.f;
  const unsigned short* mp = midb + (base + i0) * MDIM + 2 * tid;
  int i = 0;
  for (; i + 2 <= nr; i += 2){
    unsigned pk0 = *(const unsigned*)(mp + (size_t)i * MDIM);
    unsigned pk1 = *(const unsigned*)(mp + (size_t)(i + 1) * MDIM);
    float w0 = wl[i], w1 = wl[i + 1];
    a0 += w0 * bf2f((unsigned short)(pk0 & 0xffff)) + w1 * bf2f((unsigned short)(pk1 & 0xffff));
    a1 += w0 * bf2f((unsigned short)(pk0 >> 16)) + w1 * bf2f((unsigned short)(pk1 >> 16));
  }
  if (i < nr){
    unsigned pk0 = *(const unsigned*)(mp + (size_t)i * MDIM);
    float w0 = wl[i];
    a0 += w0 * bf2f((unsigned short)(pk0 & 0xffff));
    a1 += w0 * bf2f((unsigned short)(pk0 >> 16));
  }
  float* dst = bagp + (size_t)blockIdx.x * MDIM + 2 * tid;
  dst[0] = a0; dst[1] = a1;
}

// ---------------- final: exact re-rank, preds, feature copy — FLOAT32 output ----------------
__global__ __launch_bounds__(256) void kfinal(const float* __restrict__ bagp,
                                              const float* __restrict__ Wc,
                                              const float* __restrict__ bc,
                                              const float* __restrict__ emid,
                                              const float* __restrict__ ekey,
                                              const int* __restrict__ cand,
                                              float* __restrict__ out){
  __shared__ float k32[32];
  __shared__ int s32[32];
  __shared__ int ordv[32];
  __shared__ float r0[256], r1[256];
  int g = blockIdx.x, tid = threadIdx.x;
  if (tid < 32){ k32[tid] = ekey[g * 32 + tid]; s32[tid] = cand[g * 32 + tid]; }
  __syncthreads();
  if (tid == 0){
    unsigned used = 0;
    for (int a = 0; a < 32; a++){
      int best = -1;
      for (int b = 0; b < 32; b++){
        if ((used >> b) & 1u) continue;
        if (best < 0 || k32[b] > k32[best] || (k32[b] == k32[best] && s32[b] < s32[best])) best = b;
      }
      used |= 1u << best;
      ordv[a] = best;
    }
  }
  float p0 = 0.f, p1 = 0.f;
  for (int j = tid; j < 512; j += 256){
    float bv = 0.f;
    for (int s2 = 0; s2 < 128; s2++) bv += bagp[(size_t)(g * 128 + s2) * MDIM + j];
    p0 += bv * Wc[j];
    p1 += bv * Wc[512 + j];
  }
  r0[tid] = p0; r1[tid] = p1; __syncthreads();
  for (int s = 128; s > 0; s >>= 1){ if (tid < s){ r0[tid] += r0[tid + s]; r1[tid] += r1[tid + s]; } __syncthreads(); }
  if (tid == 0){
    out[g * 2 + 0] = r0[0] + bc[0];
    out[g * 2 + 1] = r1[0] + bc[1];
  }
  __syncthreads();
  for (int p = 0; p < 8; p++){
    int cc = ordv[p < 4 ? p : 24 + p];
    const float* src = emid + (size_t)(g * 32 + cc) * MDIM;
    float* dst = out + 16 + (size_t)(g * 8 + p) * MDIM;
    for (int j = tid; j < 512; j += 256) dst[j] = src[j];
  }
}

extern "C" void kernel_launch(void* const* d_in, const int* in_sizes, int n_in,
                              void* d_out, int out_size, void* d_ws, size_t ws_size,
                              hipStream_t stream){
  const int*   idxf = (const int*)d_in[0];
  const float* tfeat= (const float*)d_in[1];
  const float* W1   = (const float*)d_in[2];
  const float* b1   = (const float*)d_in[3];
  const float* Wa1  = (const float*)d_in[4];
  const float* ba1  = (const float*)d_in[5];
  const float* Wa2  = (const float*)d_in[6];
  const float* ba2  = (const float*)d_in[7];
  const float* Wc   = (const float*)d_in[8];
  const float* bc   = (const float*)d_in[9];
  float* out = (float*)d_out;
  (void)in_sizes; (void)n_in; (void)out_size; (void)ws_size;

  char* ws = (char*)d_ws;
  size_t off = 0;
  auto alloc = [&](size_t bytes){ void* p = ws + off; off += (bytes + 255) & ~(size_t)255; return p; };
  float* lv    = (float*)alloc((size_t)N_TOT * 4);
  float* tv    = (float*)alloc((size_t)N_TOT * 4);   // reused as w inside kselect
  float* maxlw = (float*)alloc(NUM_GROUP * 4);
  float* Zw    = (float*)alloc(NUM_GROUP * 4);
  int*   cand  = (int*)alloc(NUM_GROUP * 32 * 4);
  float* ekey  = (float*)alloc(NUM_GROUP * 32 * 4);
  float* emid  = (float*)alloc((size_t)NUM_GROUP * 32 * MDIM * 4);
  float* bagp  = (float*)alloc((size_t)NUM_GROUP * 128 * MDIM * 4);
  unsigned short* W1b  = (unsigned short*)alloc((size_t)MDIM * IN_CHN * 2);
  unsigned short* Wa1b = (unsigned short*)alloc((size_t)ATT_D * MDIM * 2);
  unsigned short* midb = (unsigned short*)alloc((size_t)N_TOT * MDIM * 2);
  float* w = tv;  // tv fully consumed inside kselect before w is written

  kconv<<<2304, 256, 0, stream>>>(W1, Wa1, W1b, Wa1b);
  kgemm_mid<<<3128, 256, 0, stream>>>(idxf, tfeat, W1b, b1, midb);
  kattn<<<782, 256, 0, stream>>>(midb, Wa1b, ba1, Wa2, ba2, Wc, lv, tv);
  kselect<<<8, 256, 0, stream>>>(lv, tv, maxlw, Zw, cand, w);
  kexact<<<256, 256, 0, stream>>>(idxf, tfeat, W1, b1, Wa1, ba1, Wa2, ba2, Wc, cand, maxlw, emid, ekey);
  kbag<<<1024, 256, 0, stream>>>(midb, w, bagp);
  kfinal<<<8, 256, 0, stream>>>(bagp, Wc, bc, emid, ekey, cand, out);
}

// Round 10
// 775.687 us; speedup vs baseline: 1.2826x; 1.2826x over previous
//
#include <hip/hip_runtime.h>
#include <stdint.h>

#define N_TOT 100000
#define IN_CHN 1024
#define MDIM 512
#define ATT_D 128
#define NUM_GROUP 8
#define GROUP_SIZE 12500
#define LDST 72  // padded LDS row stride in shorts (kattn only)
#define SEGR 98  // rows per kbag segment

typedef __bf16 bf16x8 __attribute__((ext_vector_type(8)));
typedef float f32x4 __attribute__((ext_vector_type(4)));
typedef unsigned short u16x8 __attribute__((ext_vector_type(8)));
typedef unsigned short u16x4 __attribute__((ext_vector_type(4)));

__device__ __forceinline__ unsigned short f2bf(float x){
  union { float f; unsigned u; } v; v.f = x;
  unsigned r = v.u + 0x7fffu + ((v.u >> 16) & 1u);
  return (unsigned short)(r >> 16);
}
__device__ __forceinline__ float bf2f(unsigned short h){
  union { unsigned u; float f; } v; v.u = ((unsigned)h) << 16; return v.f;
}
__device__ __forceinline__ void gload16(const void* g, void* l){
  __builtin_amdgcn_global_load_lds(
      (const __attribute__((address_space(1))) unsigned int*)g,
      (__attribute__((address_space(3))) unsigned int*)l, 16, 0, 0);
}

// ---------------- weight conversion f32 -> bf16 ----------------
__global__ __launch_bounds__(256) void kconv(const float* __restrict__ W1,
                                             const float* __restrict__ Wa1,
                                             unsigned short* __restrict__ W1b,
                                             unsigned short* __restrict__ Wa1b){
  int i = blockIdx.x * 256 + threadIdx.x;
  if (i < MDIM * IN_CHN) W1b[i] = f2bf(W1[i]);
  else {
    int j = i - MDIM * IN_CHN;
    if (j < ATT_D * MDIM) Wa1b[j] = f2bf(Wa1[j]);
  }
}

// ---------------- gather + convert: abf[r] = bf16(tfeat[idxf[r]])  ----------------
__global__ __launch_bounds__(256) void kprep(const int* __restrict__ idxf,
                                             const float* __restrict__ tfeat,
                                             unsigned short* __restrict__ abf){
  int r = blockIdx.x;
  int inst = idxf[r];
  float4 v = ((const float4*)(tfeat + (size_t)inst * IN_CHN))[threadIdx.x];
  u16x4 pk;
  pk[0] = f2bf(v.x); pk[1] = f2bf(v.y); pk[2] = f2bf(v.z); pk[3] = f2bf(v.w);
  *(u16x4*)(abf + (size_t)r * IN_CHN + threadIdx.x * 4) = pk;
}

// ---------------- main GEMM: mid = relu(abf @ W1b^T + b1) ----------------
// m97 structure: 128x128 tile, BK=64, both tiles via global_load_lds into
// linear LDS; XOR swizzle via pre-swizzled global source + swizzled read.
// 2 barriers per K-step. XCD-aware tile swizzle.
__global__ __launch_bounds__(256) void kgemm_mid(const unsigned short* __restrict__ abf,
                                                 const unsigned short* __restrict__ W1b,
                                                 const float* __restrict__ b1,
                                                 unsigned short* __restrict__ midb){
  __shared__ alignas(16) unsigned short Asm[128 * 64];
  __shared__ alignas(16) unsigned short Bsm[128 * 64];
  int tid = threadIdx.x;
  int bid = blockIdx.x;
  int tile = (bid & 7) * 391 + (bid >> 3);   // XCD-aware: bn-siblings adjacent on one XCD
  int bn = tile & 3, bm = tile >> 2;
  int m0 = bm * 128, n0 = bn * 128;

  int w = tid >> 6, l = tid & 63;
  int l16 = tid & 15, hi = (tid >> 4) & 3;
  int wm = tid >> 7, wn = (tid >> 6) & 1;

  // staging: per gload16 round q, wave w covers rows q*32+w*8 .. +7 (1KB each);
  // lane l -> LDS (row base+(l>>3), chunk l&7); source chunk = (l&7)^(l>>3)
  // so LDS(row, c) holds global chunk c ^ (row&7).
  const unsigned short* asrc[4];
  const unsigned short* bsrc[4];
  int dst[4];
  int scol = ((l & 7) ^ (l >> 3)) * 8;
  #pragma unroll
  for (int q = 0; q < 4; q++){
    int row = q * 32 + w * 8 + (l >> 3);
    asrc[q] = abf + (size_t)(m0 + row) * IN_CHN + scol;   // OOB rows read ws garbage; masked at store
    bsrc[q] = W1b + (size_t)(n0 + row) * IN_CHN + scol;
    dst[q] = (q * 32 + w * 8) * 64;
  }

  f32x4 acc[4][4];
  #pragma unroll
  for (int a = 0; a < 4; a++)
    #pragma unroll
    for (int b = 0; b < 4; b++) acc[a][b] = (f32x4){0.f, 0.f, 0.f, 0.f};

  for (int s = 0; s < 16; s++){
    __syncthreads();                 // previous compute done reading LDS
    #pragma unroll
    for (int q = 0; q < 4; q++){
      gload16(asrc[q] + s * 64, &Asm[dst[q]]);
      gload16(bsrc[q] + s * 64, &Bsm[dst[q]]);
    }
    __syncthreads();                 // drains DMA (implicit vmcnt(0))
    #pragma unroll
    for (int ks = 0; ks < 2; ks++){
      int g8 = ks * 4 + hi;
      int rc = (g8 ^ (l16 & 7)) * 8; // swizzled read chunk (row&7 == l16&7 for all fragments)
      bf16x8 af[4], bfr[4];
      #pragma unroll
      for (int a = 0; a < 4; a++){ int row = wm * 64 + a * 16 + l16; af[a] = *(const bf16x8*)&Asm[row * 64 + rc]; }
      #pragma unroll
      for (int b = 0; b < 4; b++){ int col = wn * 64 + b * 16 + l16; bfr[b] = *(const bf16x8*)&Bsm[col * 64 + rc]; }
      #pragma unroll
      for (int a = 0; a < 4; a++)
        #pragma unroll
        for (int b = 0; b < 4; b++)
          acc[a][b] = __builtin_amdgcn_mfma_f32_16x16x32_bf16(af[a], bfr[b], acc[a][b], 0, 0, 0);
    }
  }

  #pragma unroll
  for (int b = 0; b < 4; b++){
    int col = n0 + wn * 64 + b * 16 + l16;
    float bias = b1[col];
    #pragma unroll
    for (int a = 0; a < 4; a++){
      int rbase = m0 + wm * 64 + a * 16 + hi * 4;
      #pragma unroll
      for (int q = 0; q < 4; q++){
        int row = rbase + q;
        if (row < N_TOT){
          float v = acc[a][b][q] + bias;
          midb[(size_t)row * MDIM + col] = f2bf(fmaxf(v, 0.f));
        }
      }
    }
  }
}

// ---------------- attention MLP + fused tv ----------------
__global__ __launch_bounds__(256) void kattn(const unsigned short* __restrict__ midb,
                                             const unsigned short* __restrict__ Wa1b,
                                             const float* __restrict__ ba1,
                                             const float* __restrict__ Wa2,
                                             const float* __restrict__ ba2,
                                             const float* __restrict__ Wc,
                                             float* __restrict__ lv,
                                             float* __restrict__ tv){
  __shared__ alignas(16) unsigned short Asm[128 * LDST];
  __shared__ alignas(16) unsigned short Bsm[128 * LDST];
  __shared__ float dsh[512];
  __shared__ float part[128][2];
  int tid = threadIdx.x;
  int m0 = blockIdx.x * 128;
  for (int i = tid; i < 512; i += 256) dsh[i] = Wc[512 + i] - Wc[i];

  int lane8 = tid & 7, rq = tid >> 3;
  const unsigned short *asrc[4], *bsrc[4];
  unsigned short *adst[4], *bdst[4];
  #pragma unroll
  for (int p = 0; p < 4; p++){
    int r = p * 32 + rq;
    int rowc = m0 + r; if (rowc > N_TOT - 1) rowc = N_TOT - 1;
    asrc[p] = midb + (size_t)rowc * MDIM + lane8 * 8;
    bsrc[p] = Wa1b + (size_t)r * MDIM + lane8 * 8;
    adst[p] = &Asm[r * LDST + lane8 * 8];
    bdst[p] = &Bsm[r * LDST + lane8 * 8];
  }
  int l16 = tid & 15, hi = (tid >> 4) & 3;
  int wm = tid >> 7, wn = (tid >> 6) & 1;
  f32x4 acc[4][4];
  #pragma unroll
  for (int a = 0; a < 4; a++)
    #pragma unroll
    for (int b = 0; b < 4; b++) acc[a][b] = (f32x4){0.f, 0.f, 0.f, 0.f};
  float tpart[4] = {0.f, 0.f, 0.f, 0.f};

  for (int s = 0; s < 8; s++){
    __syncthreads();
    #pragma unroll
    for (int p = 0; p < 4; p++){
      u16x8 av = *(const u16x8*)(asrc[p] + s * 64);
      *(u16x8*)adst[p] = av;
      *(u16x8*)bdst[p] = *(const u16x8*)(bsrc[p] + s * 64);
      #pragma unroll
      for (int e = 0; e < 8; e++)
        tpart[p] += bf2f((unsigned short)av[e]) * dsh[s * 64 + lane8 * 8 + e];
    }
    __syncthreads();
    #pragma unroll
    for (int ks = 0; ks < 2; ks++){
      int off = (ks * 4 + hi) * 8;
      bf16x8 af[4], bfr[4];
      #pragma unroll
      for (int a = 0; a < 4; a++){ int row = wm * 64 + a * 16 + l16; af[a] = *(const bf16x8*)&Asm[row * LDST + off]; }
      #pragma unroll
      for (int b = 0; b < 4; b++){ int col = wn * 64 + b * 16 + l16; bfr[b] = *(const bf16x8*)&Bsm[col * LDST + off]; }
      #pragma unroll
      for (int a = 0; a < 4; a++)
        #pragma unroll
        for (int b = 0; b < 4; b++)
          acc[a][b] = __builtin_amdgcn_mfma_f32_16x16x32_bf16(af[a], bfr[b], acc[a][b], 0, 0, 0);
    }
  }
  #pragma unroll
  for (int p = 0; p < 4; p++){
    float t = tpart[p];
    t += __shfl_xor(t, 1); t += __shfl_xor(t, 2); t += __shfl_xor(t, 4);
    if (lane8 == 0){
      int row = m0 + p * 32 + rq;
      if (row < N_TOT) tv[row] = t;
    }
  }
  #pragma unroll
  for (int a = 0; a < 4; a++){
    #pragma unroll
    for (int q = 0; q < 4; q++){
      float v = 0.f;
      #pragma unroll
      for (int b = 0; b < 4; b++){
        int col = wn * 64 + b * 16 + l16;
        v += tanhf(acc[a][b][q] + ba1[col]) * Wa2[col];
      }
      #pragma unroll
      for (int off = 1; off < 16; off <<= 1) v += __shfl_xor(v, off);
      if (l16 == 0) part[wm * 64 + a * 16 + hi * 4 + q][wn] = v;
    }
  }
  __syncthreads();
  if (tid < 128){
    int row = m0 + tid;
    if (row < N_TOT) lv[row] = part[tid][0] + part[tid][1] + ba2[0];
  }
}

// ---------------- per-group stats + top/bottom-16 + fused softmax weights ----------------
__global__ __launch_bounds__(256) void kselect(const float* __restrict__ lv,
                                               const float* __restrict__ tv,
                                               float* __restrict__ maxlw, float* __restrict__ Zw,
                                               int* __restrict__ cand,
                                               float* __restrict__ w){
  __shared__ float keys[GROUP_SIZE];
  __shared__ unsigned char flg[GROUP_SIZE];
  __shared__ float rk[256];
  __shared__ int ri[256];
  __shared__ float sbc;
  int g = blockIdx.x, tid = threadIdx.x;
  const float* lg = lv + (size_t)g * GROUP_SIZE;
  const float* tg = tv + (size_t)g * GROUP_SIZE;

  float mx = -1e30f;
  for (int i = tid; i < GROUP_SIZE; i += 256) mx = fmaxf(mx, lg[i]);
  rk[tid] = mx; __syncthreads();
  for (int s = 128; s > 0; s >>= 1){ if (tid < s) rk[tid] = fmaxf(rk[tid], rk[tid + s]); __syncthreads(); }
  if (tid == 0) sbc = rk[0];
  __syncthreads();
  float maxl = sbc;

  float z = 0.f;
  for (int i = tid; i < GROUP_SIZE; i += 256){
    float ez = expf(lg[i] - maxl);
    z += ez;
    keys[i] = ez * tg[i];
    flg[i] = 0;
  }
  rk[tid] = z; __syncthreads();
  for (int s = 128; s > 0; s >>= 1){ if (tid < s) rk[tid] += rk[tid + s]; __syncthreads(); }
  if (tid == 0){ maxlw[g] = maxl; Zw[g] = rk[0]; }
  __syncthreads();
  float invZ = 1.0f / rk[0];
  for (int i = tid; i < GROUP_SIZE; i += 256)
    w[(size_t)g * GROUP_SIZE + i] = expf(lg[i] - maxl) * invZ;

  for (int it = 0; it < 16; it++){
    float bk = -1e30f; int bi = -1;
    for (int i = tid; i < GROUP_SIZE; i += 256)
      if (!flg[i]){ float k = keys[i]; if (k > bk || (k == bk && (unsigned)i < (unsigned)bi)){ bk = k; bi = i; } }
    rk[tid] = bk; ri[tid] = bi; __syncthreads();
    for (int s = 128; s > 0; s >>= 1){
      if (tid < s){
        if (rk[tid + s] > rk[tid] || (rk[tid + s] == rk[tid] && (unsigned)ri[tid + s] < (unsigned)ri[tid])){
          rk[tid] = rk[tid + s]; ri[tid] = ri[tid + s];
        }
      }
      __syncthreads();
    }
    if (tid == 0){ cand[g * 32 + it] = ri[0]; flg[ri[0]] = 1; }
    __syncthreads();
  }
  for (int it = 0; it < 16; it++){
    float bk = 1e30f; int bi = -1;
    for (int i = tid; i < GROUP_SIZE; i += 256)
      if (!flg[i]){ float k = keys[i]; if (k < bk || (k == bk && i > bi)){ bk = k; bi = i; } }
    rk[tid] = bk; ri[tid] = bi; __syncthreads();
    for (int s = 128; s > 0; s >>= 1){
      if (tid < s){
        if (rk[tid + s] < rk[tid] || (rk[tid + s] == rk[tid] && ri[tid + s] > ri[tid])){
          rk[tid] = rk[tid + s]; ri[tid] = ri[tid + s];
        }
      }
      __syncthreads();
    }
    if (tid == 0){ cand[g * 32 + 16 + it] = ri[0]; flg[ri[0]] = 1; }
    __syncthreads();
  }
}

// ---------------- exact f32 recompute of 256 candidate rows ----------------
__global__ __launch_bounds__(256) void kexact(const int* __restrict__ idxf,
                                              const float* __restrict__ tfeat,
                                              const float* __restrict__ W1,
                                              const float* __restrict__ b1,
                                              const float* __restrict__ Wa1,
                                              const float* __restrict__ ba1,
                                              const float* __restrict__ Wa2,
                                              const float* __restrict__ ba2,
                                              const float* __restrict__ Wc,
                                              const int* __restrict__ cand,
                                              const float* __restrict__ maxlw,
                                              float* __restrict__ emid, float* __restrict__ ekey){
  __shared__ float subs[1024];
  __shared__ float midc[512];
  __shared__ float hs[128];
  __shared__ float red[256];
  __shared__ float tsh;
  int bid = blockIdx.x; int g = bid >> 5, c = bid & 31; int tid = threadIdx.x;
  int s = cand[g * 32 + c];
  int inst = idxf[g * GROUP_SIZE + s];
  ((float4*)subs)[tid] = ((const float4*)(tfeat + (size_t)inst * IN_CHN))[tid];
  __syncthreads();

  float a0 = b1[tid], a1 = b1[tid + 256];
  const float4* w0 = (const float4*)(W1 + (size_t)tid * IN_CHN);
  const float4* w1 = (const float4*)(W1 + ((size_t)tid + 256) * IN_CHN);
  const float4* s4 = (const float4*)subs;
  #pragma unroll 4
  for (int k = 0; k < 256; k++){
    float4 sv = s4[k], wva = w0[k], wvb = w1[k];
    a0 += sv.x * wva.x + sv.y * wva.y + sv.z * wva.z + sv.w * wva.w;
    a1 += sv.x * wvb.x + sv.y * wvb.y + sv.z * wvb.z + sv.w * wvb.w;
  }
  a0 = fmaxf(a0, 0.f); a1 = fmaxf(a1, 0.f);
  midc[tid] = a0; midc[tid + 256] = a1;
  size_t eo = (size_t)(g * 32 + c) * MDIM;
  emid[eo + tid] = a0; emid[eo + tid + 256] = a1;
  __syncthreads();

  if (tid < 128){
    const float4* wr = (const float4*)(Wa1 + (size_t)tid * MDIM);
    const float4* m4 = (const float4*)midc;
    float h = ba1[tid];
    #pragma unroll 4
    for (int j = 0; j < 128; j++){
      float4 mv = m4[j], wv = wr[j];
      h += mv.x * wv.x + mv.y * wv.y + mv.z * wv.z + mv.w * wv.w;
    }
    hs[tid] = tanhf(h) * Wa2[tid];
  }
  __syncthreads();

  float tp = midc[tid] * (Wc[512 + tid] - Wc[tid]) + midc[tid + 256] * (Wc[768 + tid] - Wc[256 + tid]);
  red[tid] = tp; __syncthreads();
  for (int st = 128; st > 0; st >>= 1){ if (tid < st) red[tid] += red[tid + st]; __syncthreads(); }
  if (tid == 0) tsh = red[0];
  __syncthreads();
  red[tid] = (tid < 128) ? hs[tid] : 0.f; __syncthreads();
  for (int st = 128; st > 0; st >>= 1){ if (tid < st) red[tid] += red[tid + st]; __syncthreads(); }
  if (tid == 0){
    float lval = red[0] + ba2[0];
    ekey[g * 32 + c] = expf(lval - maxlw[g]) * tsh;
  }
}

// ---------------- weighted bag-sum: 128 segments x 8 groups, partials ----------------
__global__ __launch_bounds__(256) void kbag(const unsigned short* __restrict__ midb,
                                            const float* __restrict__ w,
                                            float* __restrict__ bagp){
  __shared__ float wl[SEGR];
  int g = blockIdx.x >> 7, seg = blockIdx.x & 127, tid = threadIdx.x;
  int i0 = seg * SEGR;
  int nr = GROUP_SIZE - i0; if (nr > SEGR) nr = SEGR;
  size_t base = (size_t)g * GROUP_SIZE;
  if (tid < nr) wl[tid] = w[base + i0 + tid];
  __syncthreads();
  float a0 = 0.f, a1 = 0.f;
  const unsigned short* mp = midb + (base + i0) * MDIM + 2 * tid;
  int i = 0;
  for (; i + 2 <= nr; i += 2){
    unsigned pk0 = *(const unsigned*)(mp + (size_t)i * MDIM);
    unsigned pk1 = *(const unsigned*)(mp + (size_t)(i + 1) * MDIM);
    float w0 = wl[i], w1 = wl[i + 1];
    a0 += w0 * bf2f((unsigned short)(pk0 & 0xffff)) + w1 * bf2f((unsigned short)(pk1 & 0xffff));
    a1 += w0 * bf2f((unsigned short)(pk0 >> 16)) + w1 * bf2f((unsigned short)(pk1 >> 16));
  }
  if (i < nr){
    unsigned pk0 = *(const unsigned*)(mp + (size_t)i * MDIM);
    float w0 = wl[i];
    a0 += w0 * bf2f((unsigned short)(pk0 & 0xffff));
    a1 += w0 * bf2f((unsigned short)(pk0 >> 16));
  }
  float* dst = bagp + (size_t)blockIdx.x * MDIM + 2 * tid;
  dst[0] = a0; dst[1] = a1;
}

// ---------------- final: exact re-rank, preds, feature copy — FLOAT32 output ----------------
__global__ __launch_bounds__(256) void kfinal(const float* __restrict__ bagp,
                                              const float* __restrict__ Wc,
                                              const float* __restrict__ bc,
                                              const float* __restrict__ emid,
                                              const float* __restrict__ ekey,
                                              const int* __restrict__ cand,
                                              float* __restrict__ out){
  __shared__ float k32[32];
  __shared__ int s32[32];
  __shared__ int ordv[32];
  __shared__ float r0[256], r1[256];
  int g = blockIdx.x, tid = threadIdx.x;
  if (tid < 32){ k32[tid] = ekey[g * 32 + tid]; s32[tid] = cand[g * 32 + tid]; }
  __syncthreads();
  if (tid == 0){
    unsigned used = 0;
    for (int a = 0; a < 32; a++){
      int best = -1;
      for (int b = 0; b < 32; b++){
        if ((used >> b) & 1u) continue;
        if (best < 0 || k32[b] > k32[best] || (k32[b] == k32[best] && s32[b] < s32[best])) best = b;
      }
      used |= 1u << best;
      ordv[a] = best;
    }
  }
  float p0 = 0.f, p1 = 0.f;
  for (int j = tid; j < 512; j += 256){
    float bv = 0.f;
    for (int s2 = 0; s2 < 128; s2++) bv += bagp[(size_t)(g * 128 + s2) * MDIM + j];
    p0 += bv * Wc[j];
    p1 += bv * Wc[512 + j];
  }
  r0[tid] = p0; r1[tid] = p1; __syncthreads();
  for (int s = 128; s > 0; s >>= 1){ if (tid < s){ r0[tid] += r0[tid + s]; r1[tid] += r1[tid + s]; } __syncthreads(); }
  if (tid == 0){
    out[g * 2 + 0] = r0[0] + bc[0];
    out[g * 2 + 1] = r1[0] + bc[1];
  }
  __syncthreads();
  for (int p = 0; p < 8; p++){
    int cc = ordv[p < 4 ? p : 24 + p];
    const float* src = emid + (size_t)(g * 32 + cc) * MDIM;
    float* dst = out + 16 + (size_t)(g * 8 + p) * MDIM;
    for (int j = tid; j < 512; j += 256) dst[j] = src[j];
  }
}

extern "C" void kernel_launch(void* const* d_in, const int* in_sizes, int n_in,
                              void* d_out, int out_size, void* d_ws, size_t ws_size,
                              hipStream_t stream){
  const int*   idxf = (const int*)d_in[0];
  const float* tfeat= (const float*)d_in[1];
  const float* W1   = (const float*)d_in[2];
  const float* b1   = (const float*)d_in[3];
  const float* Wa1  = (const float*)d_in[4];
  const float* ba1  = (const float*)d_in[5];
  const float* Wa2  = (const float*)d_in[6];
  const float* ba2  = (const float*)d_in[7];
  const float* Wc   = (const float*)d_in[8];
  const float* bc   = (const float*)d_in[9];
  float* out = (float*)d_out;
  (void)in_sizes; (void)n_in; (void)out_size; (void)ws_size;

  char* ws = (char*)d_ws;
  size_t off = 0;
  auto alloc = [&](size_t bytes){ void* p = ws + off; off += (bytes + 255) & ~(size_t)255; return p; };
  float* lv    = (float*)alloc((size_t)N_TOT * 4);
  float* tv    = (float*)alloc((size_t)N_TOT * 4);   // reused as w inside kselect
  float* maxlw = (float*)alloc(NUM_GROUP * 4);
  float* Zw    = (float*)alloc(NUM_GROUP * 4);
  int*   cand  = (int*)alloc(NUM_GROUP * 32 * 4);
  float* ekey  = (float*)alloc(NUM_GROUP * 32 * 4);
  float* emid  = (float*)alloc((size_t)NUM_GROUP * 32 * MDIM * 4);
  float* bagp  = (float*)alloc((size_t)NUM_GROUP * 128 * MDIM * 4);
  unsigned short* W1b  = (unsigned short*)alloc((size_t)MDIM * IN_CHN * 2);
  unsigned short* Wa1b = (unsigned short*)alloc((size_t)ATT_D * MDIM * 2);
  unsigned short* abf  = (unsigned short*)alloc((size_t)N_TOT * IN_CHN * 2);
  unsigned short* midb = (unsigned short*)alloc((size_t)N_TOT * MDIM * 2);
  float* w = tv;  // tv fully consumed inside kselect before w is written

  kconv<<<2304, 256, 0, stream>>>(W1, Wa1, W1b, Wa1b);
  kprep<<<N_TOT, 256, 0, stream>>>(idxf, tfeat, abf);
  kgemm_mid<<<3128, 256, 0, stream>>>(abf, W1b, b1, midb);
  kattn<<<782, 256, 0, stream>>>(midb, Wa1b, ba1, Wa2, ba2, Wc, lv, tv);
  kselect<<<8, 256, 0, stream>>>(lv, tv, maxlw, Zw, cand, w);
  kexact<<<256, 256, 0, stream>>>(idxf, tfeat, W1, b1, Wa1, ba1, Wa2, ba2, Wc, cand, maxlw, emid, ekey);
  kbag<<<1024, 256, 0, stream>>>(midb, w, bagp);
  kfinal<<<8, 256, 0, stream>>>(bagp, Wc, bc, emid, ekey, cand, out);
}

// Round 11
// 731.603 us; speedup vs baseline: 1.3599x; 1.0603x over previous
//
#include <hip/hip_runtime.h>
#include <stdint.h>

#define N_TOT 100000
#define IN_CHN 1024
#define MDIM 512
#define ATT_D 128
#define NUM_GROUP 8
#define GROUP_SIZE 12500
#define LDST 72  // padded LDS row stride in shorts (kattn only)
#define SEGR 98  // rows per kbag segment

typedef __bf16 bf16x8 __attribute__((ext_vector_type(8)));
typedef float f32x4 __attribute__((ext_vector_type(4)));
typedef unsigned short u16x8 __attribute__((ext_vector_type(8)));

__device__ __forceinline__ unsigned short f2bf(float x){
  union { float f; unsigned u; } v; v.f = x;
  unsigned r = v.u + 0x7fffu + ((v.u >> 16) & 1u);
  return (unsigned short)(r >> 16);
}
__device__ __forceinline__ float bf2f(unsigned short h){
  union { unsigned u; float f; } v; v.u = ((unsigned)h) << 16; return v.f;
}
__device__ __forceinline__ void gload16(const void* g, void* l){
  __builtin_amdgcn_global_load_lds(
      (const __attribute__((address_space(1))) unsigned int*)g,
      (__attribute__((address_space(3))) unsigned int*)l, 16, 0, 0);
}

// ---------------- weight conversion f32 -> bf16 ----------------
__global__ __launch_bounds__(256) void kconv(const float* __restrict__ W1,
                                             const float* __restrict__ Wa1,
                                             unsigned short* __restrict__ W1b,
                                             unsigned short* __restrict__ Wa1b){
  int i = blockIdx.x * 256 + threadIdx.x;
  if (i < MDIM * IN_CHN) W1b[i] = f2bf(W1[i]);
  else {
    int j = i - MDIM * IN_CHN;
    if (j < ATT_D * MDIM) Wa1b[j] = f2bf(Wa1[j]);
  }
}

// ---------------- main gather+GEMM: mid = relu(tfeat[idx] @ W1b^T + b1) ----------------
// 128x128 tile, BK=32. A: f32, gathered per-lane global_load_lds, swizzle c^=row&7.
// B: bf16 global_load_lds, swizzle c^=(row>>1)&3. 24KB LDS, 2 barriers/step.
__global__ __launch_bounds__(256) void kgemm_mid(const int* __restrict__ idxf,
                                                 const float* __restrict__ tfeat,
                                                 const unsigned short* __restrict__ W1b,
                                                 const float* __restrict__ b1,
                                                 unsigned short* __restrict__ midb){
  __shared__ alignas(16) float Af[128 * 32];          // 16 KB, rows of 32 f32 (8 chunks x 16B)
  __shared__ alignas(16) unsigned short Bs[128 * 32]; // 8 KB, rows of 32 bf16 (4 chunks x 16B)
  __shared__ int gsm[128];
  int tid = threadIdx.x;
  int bid = blockIdx.x;
  int tile = (bid & 7) * 391 + (bid >> 3);   // XCD-aware: bn-siblings adjacent on one XCD
  int bn = tile & 3, bm = tile >> 2;
  int m0 = bm * 128, n0 = bn * 128;
  if (tid < 128){ int r = m0 + tid; gsm[tid] = idxf[r < N_TOT ? r : 0]; }
  __syncthreads();

  int w = tid >> 6, l = tid & 63;
  int l16 = tid & 15, hi = (tid >> 4) & 3;
  int wm = tid >> 7, wn = (tid >> 6) & 1;

  // A staging: 4 rounds; lane l -> row base+(l>>3), chunk l&7 (16B f32).
  // LDS(row,c) must hold source chunk c^(row&7) -> source chunk = (l&7)^(l>>3).
  const float* asrc[4]; float* adst[4];
  #pragma unroll
  for (int q = 0; q < 4; q++){
    int rowl = q * 32 + w * 8 + (l >> 3);
    asrc[q] = tfeat + (size_t)gsm[rowl] * IN_CHN + (((l & 7) ^ (l >> 3)) << 2);
    adst[q] = &Af[(q * 32 + w * 8) * 32];
  }
  // B staging: 2 rounds; lane l -> row base+(l>>2), chunk l&3 (16B bf16).
  // LDS(row,c) holds source chunk c^((row>>1)&3) -> source chunk = (l&3)^((l>>3)&3).
  const unsigned short* bsrc[2]; unsigned short* bdst[2];
  #pragma unroll
  for (int q = 0; q < 2; q++){
    int rowl = q * 64 + w * 16 + (l >> 2);
    bsrc[q] = W1b + (size_t)(n0 + rowl) * IN_CHN + (((l & 3) ^ ((l >> 3) & 3)) << 3);
    bdst[q] = &Bs[(q * 64 + w * 16) * 32];
  }

  f32x4 acc[4][4];
  #pragma unroll
  for (int a = 0; a < 4; a++)
    #pragma unroll
    for (int b = 0; b < 4; b++) acc[a][b] = (f32x4){0.f, 0.f, 0.f, 0.f};

  int r7 = l16 & 7;
  int bc = (l16 >> 1) & 3;

  for (int s = 0; s < 32; s++){
    __syncthreads();                 // previous compute done reading LDS
    #pragma unroll
    for (int q = 0; q < 4; q++) gload16(asrc[q] + s * 32, adst[q]);
    #pragma unroll
    for (int q = 0; q < 2; q++) gload16(bsrc[q] + s * 32, bdst[q]);
    __syncthreads();                 // drains DMA (implicit vmcnt(0))

    bf16x8 af[4], bfr[4];
    #pragma unroll
    for (int a = 0; a < 4; a++){
      int row = wm * 64 + a * 16 + l16;
      f32x4 lo = *(const f32x4*)&Af[row * 32 + (((2 * hi) ^ r7) << 2)];
      f32x4 hi4 = *(const f32x4*)&Af[row * 32 + (((2 * hi + 1) ^ r7) << 2)];
      bf16x8 pk;
      pk[0] = (__bf16)lo[0]; pk[1] = (__bf16)lo[1]; pk[2] = (__bf16)lo[2]; pk[3] = (__bf16)lo[3];
      pk[4] = (__bf16)hi4[0]; pk[5] = (__bf16)hi4[1]; pk[6] = (__bf16)hi4[2]; pk[7] = (__bf16)hi4[3];
      af[a] = pk;
    }
    #pragma unroll
    for (int b = 0; b < 4; b++){
      int row = wn * 64 + b * 16 + l16;
      bfr[b] = *(const bf16x8*)&Bs[row * 32 + ((hi ^ bc) << 3)];
    }
    #pragma unroll
    for (int a = 0; a < 4; a++)
      #pragma unroll
      for (int b = 0; b < 4; b++)
        acc[a][b] = __builtin_amdgcn_mfma_f32_16x16x32_bf16(af[a], bfr[b], acc[a][b], 0, 0, 0);
  }

  #pragma unroll
  for (int b = 0; b < 4; b++){
    int col = n0 + wn * 64 + b * 16 + l16;
    float bias = b1[col];
    #pragma unroll
    for (int a = 0; a < 4; a++){
      int rbase = m0 + wm * 64 + a * 16 + hi * 4;
      #pragma unroll
      for (int q = 0; q < 4; q++){
        int row = rbase + q;
        if (row < N_TOT){
          float v = acc[a][b][q] + bias;
          midb[(size_t)row * MDIM + col] = f2bf(fmaxf(v, 0.f));
        }
      }
    }
  }
}

// ---------------- attention MLP + fused tv ----------------
__global__ __launch_bounds__(256) void kattn(const unsigned short* __restrict__ midb,
                                             const unsigned short* __restrict__ Wa1b,
                                             const float* __restrict__ ba1,
                                             const float* __restrict__ Wa2,
                                             const float* __restrict__ ba2,
                                             const float* __restrict__ Wc,
                                             float* __restrict__ lv,
                                             float* __restrict__ tv){
  __shared__ alignas(16) unsigned short Asm[128 * LDST];
  __shared__ alignas(16) unsigned short Bsm[128 * LDST];
  __shared__ float dsh[512];
  __shared__ float part[128][2];
  int tid = threadIdx.x;
  int m0 = blockIdx.x * 128;
  for (int i = tid; i < 512; i += 256) dsh[i] = Wc[512 + i] - Wc[i];

  int lane8 = tid & 7, rq = tid >> 3;
  const unsigned short *asrc[4], *bsrc[4];
  unsigned short *adst[4], *bdst[4];
  #pragma unroll
  for (int p = 0; p < 4; p++){
    int r = p * 32 + rq;
    int rowc = m0 + r; if (rowc > N_TOT - 1) rowc = N_TOT - 1;
    asrc[p] = midb + (size_t)rowc * MDIM + lane8 * 8;
    bsrc[p] = Wa1b + (size_t)r * MDIM + lane8 * 8;
    adst[p] = &Asm[r * LDST + lane8 * 8];
    bdst[p] = &Bsm[r * LDST + lane8 * 8];
  }
  int l16 = tid & 15, hi = (tid >> 4) & 3;
  int wm = tid >> 7, wn = (tid >> 6) & 1;
  f32x4 acc[4][4];
  #pragma unroll
  for (int a = 0; a < 4; a++)
    #pragma unroll
    for (int b = 0; b < 4; b++) acc[a][b] = (f32x4){0.f, 0.f, 0.f, 0.f};
  float tpart[4] = {0.f, 0.f, 0.f, 0.f};

  for (int s = 0; s < 8; s++){
    __syncthreads();
    #pragma unroll
    for (int p = 0; p < 4; p++){
      u16x8 av = *(const u16x8*)(asrc[p] + s * 64);
      *(u16x8*)adst[p] = av;
      *(u16x8*)bdst[p] = *(const u16x8*)(bsrc[p] + s * 64);
      #pragma unroll
      for (int e = 0; e < 8; e++)
        tpart[p] += bf2f((unsigned short)av[e]) * dsh[s * 64 + lane8 * 8 + e];
    }
    __syncthreads();
    #pragma unroll
    for (int ks = 0; ks < 2; ks++){
      int off = (ks * 4 + hi) * 8;
      bf16x8 af[4], bfr[4];
      #pragma unroll
      for (int a = 0; a < 4; a++){ int row = wm * 64 + a * 16 + l16; af[a] = *(const bf16x8*)&Asm[row * LDST + off]; }
      #pragma unroll
      for (int b = 0; b < 4; b++){ int col = wn * 64 + b * 16 + l16; bfr[b] = *(const bf16x8*)&Bsm[col * LDST + off]; }
      #pragma unroll
      for (int a = 0; a < 4; a++)
        #pragma unroll
        for (int b = 0; b < 4; b++)
          acc[a][b] = __builtin_amdgcn_mfma_f32_16x16x32_bf16(af[a], bfr[b], acc[a][b], 0, 0, 0);
    }
  }
  #pragma unroll
  for (int p = 0; p < 4; p++){
    float t = tpart[p];
    t += __shfl_xor(t, 1); t += __shfl_xor(t, 2); t += __shfl_xor(t, 4);
    if (lane8 == 0){
      int row = m0 + p * 32 + rq;
      if (row < N_TOT) tv[row] = t;
    }
  }
  #pragma unroll
  for (int a = 0; a < 4; a++){
    #pragma unroll
    for (int q = 0; q < 4; q++){
      float v = 0.f;
      #pragma unroll
      for (int b = 0; b < 4; b++){
        int col = wn * 64 + b * 16 + l16;
        v += tanhf(acc[a][b][q] + ba1[col]) * Wa2[col];
      }
      #pragma unroll
      for (int off = 1; off < 16; off <<= 1) v += __shfl_xor(v, off);
      if (l16 == 0) part[wm * 64 + a * 16 + hi * 4 + q][wn] = v;
    }
  }
  __syncthreads();
  if (tid < 128){
    int row = m0 + tid;
    if (row < N_TOT) lv[row] = part[tid][0] + part[tid][1] + ba2[0];
  }
}

// ---------------- per-group stats + top/bottom-16 + fused softmax weights ----------------
__global__ __launch_bounds__(256) void kselect(const float* __restrict__ lv,
                                               const float* __restrict__ tv,
                                               float* __restrict__ maxlw, float* __restrict__ Zw,
                                               int* __restrict__ cand,
                                               float* __restrict__ w){
  __shared__ float keys[GROUP_SIZE];
  __shared__ unsigned char flg[GROUP_SIZE];
  __shared__ float rk[256];
  __shared__ int ri[256];
  __shared__ float sbc;
  int g = blockIdx.x, tid = threadIdx.x;
  const float* lg = lv + (size_t)g * GROUP_SIZE;
  const float* tg = tv + (size_t)g * GROUP_SIZE;

  float mx = -1e30f;
  for (int i = tid; i < GROUP_SIZE; i += 256) mx = fmaxf(mx, lg[i]);
  rk[tid] = mx; __syncthreads();
  for (int s = 128; s > 0; s >>= 1){ if (tid < s) rk[tid] = fmaxf(rk[tid], rk[tid + s]); __syncthreads(); }
  if (tid == 0) sbc = rk[0];
  __syncthreads();
  float maxl = sbc;

  float z = 0.f;
  for (int i = tid; i < GROUP_SIZE; i += 256){
    float ez = expf(lg[i] - maxl);
    z += ez;
    keys[i] = ez * tg[i];
    flg[i] = 0;
  }
  rk[tid] = z; __syncthreads();
  for (int s = 128; s > 0; s >>= 1){ if (tid < s) rk[tid] += rk[tid + s]; __syncthreads(); }
  if (tid == 0){ maxlw[g] = maxl; Zw[g] = rk[0]; }
  __syncthreads();
  float invZ = 1.0f / rk[0];
  for (int i = tid; i < GROUP_SIZE; i += 256)
    w[(size_t)g * GROUP_SIZE + i] = expf(lg[i] - maxl) * invZ;

  for (int it = 0; it < 16; it++){
    float bk = -1e30f; int bi = -1;
    for (int i = tid; i < GROUP_SIZE; i += 256)
      if (!flg[i]){ float k = keys[i]; if (k > bk || (k == bk && (unsigned)i < (unsigned)bi)){ bk = k; bi = i; } }
    rk[tid] = bk; ri[tid] = bi; __syncthreads();
    for (int s = 128; s > 0; s >>= 1){
      if (tid < s){
        if (rk[tid + s] > rk[tid] || (rk[tid + s] == rk[tid] && (unsigned)ri[tid + s] < (unsigned)ri[tid])){
          rk[tid] = rk[tid + s]; ri[tid] = ri[tid + s];
        }
      }
      __syncthreads();
    }
    if (tid == 0){ cand[g * 32 + it] = ri[0]; flg[ri[0]] = 1; }
    __syncthreads();
  }
  for (int it = 0; it < 16; it++){
    float bk = 1e30f; int bi = -1;
    for (int i = tid; i < GROUP_SIZE; i += 256)
      if (!flg[i]){ float k = keys[i]; if (k < bk || (k == bk && i > bi)){ bk = k; bi = i; } }
    rk[tid] = bk; ri[tid] = bi; __syncthreads();
    for (int s = 128; s > 0; s >>= 1){
      if (tid < s){
        if (rk[tid + s] < rk[tid] || (rk[tid + s] == rk[tid] && ri[tid + s] > ri[tid])){
          rk[tid] = rk[tid + s]; ri[tid] = ri[tid + s];
        }
      }
      __syncthreads();
    }
    if (tid == 0){ cand[g * 32 + 16 + it] = ri[0]; flg[ri[0]] = 1; }
    __syncthreads();
  }
}

// ---------------- exact f32 recompute of 256 candidate rows ----------------
__global__ __launch_bounds__(256) void kexact(const int* __restrict__ idxf,
                                              const float* __restrict__ tfeat,
                                              const float* __restrict__ W1,
                                              const float* __restrict__ b1,
                                              const float* __restrict__ Wa1,
                                              const float* __restrict__ ba1,
                                              const float* __restrict__ Wa2,
                                              const float* __restrict__ ba2,
                                              const float* __restrict__ Wc,
                                              const int* __restrict__ cand,
                                              const float* __restrict__ maxlw,
                                              float* __restrict__ emid, float* __restrict__ ekey){
  __shared__ float subs[1024];
  __shared__ float midc[512];
  __shared__ float hs[128];
  __shared__ float red[256];
  __shared__ float tsh;
  int bid = blockIdx.x; int g = bid >> 5, c = bid & 31; int tid = threadIdx.x;
  int s = cand[g * 32 + c];
  int inst = idxf[g * GROUP_SIZE + s];
  ((float4*)subs)[tid] = ((const float4*)(tfeat + (size_t)inst * IN_CHN))[tid];
  __syncthreads();

  float a0 = b1[tid], a1 = b1[tid + 256];
  const float4* w0 = (const float4*)(W1 + (size_t)tid * IN_CHN);
  const float4* w1 = (const float4*)(W1 + ((size_t)tid + 256) * IN_CHN);
  const float4* s4 = (const float4*)subs;
  #pragma unroll 4
  for (int k = 0; k < 256; k++){
    float4 sv = s4[k], wva = w0[k], wvb = w1[k];
    a0 += sv.x * wva.x + sv.y * wva.y + sv.z * wva.z + sv.w * wva.w;
    a1 += sv.x * wvb.x + sv.y * wvb.y + sv.z * wvb.z + sv.w * wvb.w;
  }
  a0 = fmaxf(a0, 0.f); a1 = fmaxf(a1, 0.f);
  midc[tid] = a0; midc[tid + 256] = a1;
  size_t eo = (size_t)(g * 32 + c) * MDIM;
  emid[eo + tid] = a0; emid[eo + tid + 256] = a1;
  __syncthreads();

  if (tid < 128){
    const float4* wr = (const float4*)(Wa1 + (size_t)tid * MDIM);
    const float4* m4 = (const float4*)midc;
    float h = ba1[tid];
    #pragma unroll 4
    for (int j = 0; j < 128; j++){
      float4 mv = m4[j], wv = wr[j];
      h += mv.x * wv.x + mv.y * wv.y + mv.z * wv.z + mv.w * wv.w;
    }
    hs[tid] = tanhf(h) * Wa2[tid];
  }
  __syncthreads();

  float tp = midc[tid] * (Wc[512 + tid] - Wc[tid]) + midc[tid + 256] * (Wc[768 + tid] - Wc[256 + tid]);
  red[tid] = tp; __syncthreads();
  for (int st = 128; st > 0; st >>= 1){ if (tid < st) red[tid] += red[tid + st]; __syncthreads(); }
  if (tid == 0) tsh = red[0];
  __syncthreads();
  red[tid] = (tid < 128) ? hs[tid] : 0.f; __syncthreads();
  for (int st = 128; st > 0; st >>= 1){ if (tid < st) red[tid] += red[tid + st]; __syncthreads(); }
  if (tid == 0){
    float lval = red[0] + ba2[0];
    ekey[g * 32 + c] = expf(lval - maxlw[g]) * tsh;
  }
}

// ---------------- weighted bag-sum: 128 segments x 8 groups, partials ----------------
__global__ __launch_bounds__(256) void kbag(const unsigned short* __restrict__ midb,
                                            const float* __restrict__ w,
                                            float* __restrict__ bagp){
  __shared__ float wl[SEGR];
  int g = blockIdx.x >> 7, seg = blockIdx.x & 127, tid = threadIdx.x;
  int i0 = seg * SEGR;
  int nr = GROUP_SIZE - i0; if (nr > SEGR) nr = SEGR;
  size_t base = (size_t)g * GROUP_SIZE;
  if (tid < nr) wl[tid] = w[base + i0 + tid];
  __syncthreads();
  float a0 = 0.f, a1 = 0.f;
  const unsigned short* mp = midb + (base + i0) * MDIM + 2 * tid;
  int i = 0;
  for (; i + 2 <= nr; i += 2){
    unsigned pk0 = *(const unsigned*)(mp + (size_t)i * MDIM);
    unsigned pk1 = *(const unsigned*)(mp + (size_t)(i + 1) * MDIM);
    float w0 = wl[i], w1 = wl[i + 1];
    a0 += w0 * bf2f((unsigned short)(pk0 & 0xffff)) + w1 * bf2f((unsigned short)(pk1 & 0xffff));
    a1 += w0 * bf2f((unsigned short)(pk0 >> 16)) + w1 * bf2f((unsigned short)(pk1 >> 16));
  }
  if (i < nr){
    unsigned pk0 = *(const unsigned*)(mp + (size_t)i * MDIM);
    float w0 = wl[i];
    a0 += w0 * bf2f((unsigned short)(pk0 & 0xffff));
    a1 += w0 * bf2f((unsigned short)(pk0 >> 16));
  }
  float* dst = bagp + (size_t)blockIdx.x * MDIM + 2 * tid;
  dst[0] = a0; dst[1] = a1;
}

// ---------------- final: exact re-rank, preds, feature copy — FLOAT32 output ----------------
__global__ __launch_bounds__(256) void kfinal(const float* __restrict__ bagp,
                                              const float* __restrict__ Wc,
                                              const float* __restrict__ bc,
                                              const float* __restrict__ emid,
                                              const float* __restrict__ ekey,
                                              const int* __restrict__ cand,
                                              float* __restrict__ out){
  __shared__ float k32[32];
  __shared__ int s32[32];
  __shared__ int ordv[32];
  __shared__ float r0[256], r1[256];
  int g = blockIdx.x, tid = threadIdx.x;
  if (tid < 32){ k32[tid] = ekey[g * 32 + tid]; s32[tid] = cand[g * 32 + tid]; }
  __syncthreads();
  if (tid == 0){
    unsigned used = 0;
    for (int a = 0; a < 32; a++){
      int best = -1;
      for (int b = 0; b < 32; b++){
        if ((used >> b) & 1u) continue;
        if (best < 0 || k32[b] > k32[best] || (k32[b] == k32[best] && s32[b] < s32[best])) best = b;
      }
      used |= 1u << best;
      ordv[a] = best;
    }
  }
  float p0 = 0.f, p1 = 0.f;
  for (int j = tid; j < 512; j += 256){
    float bv = 0.f;
    for (int s2 = 0; s2 < 128; s2++) bv += bagp[(size_t)(g * 128 + s2) * MDIM + j];
    p0 += bv * Wc[j];
    p1 += bv * Wc[512 + j];
  }
  r0[tid] = p0; r1[tid] = p1; __syncthreads();
  for (int s = 128; s > 0; s >>= 1){ if (tid < s){ r0[tid] += r0[tid + s]; r1[tid] += r1[tid + s]; } __syncthreads(); }
  if (tid == 0){
    out[g * 2 + 0] = r0[0] + bc[0];
    out[g * 2 + 1] = r1[0] + bc[1];
  }
  __syncthreads();
  for (int p = 0; p < 8; p++){
    int cc = ordv[p < 4 ? p : 24 + p];
    const float* src = emid + (size_t)(g * 32 + cc) * MDIM;
    float* dst = out + 16 + (size_t)(g * 8 + p) * MDIM;
    for (int j = tid; j < 512; j += 256) dst[j] = src[j];
  }
}

extern "C" void kernel_launch(void* const* d_in, const int* in_sizes, int n_in,
                              void* d_out, int out_size, void* d_ws, size_t ws_size,
                              hipStream_t stream){
  const int*   idxf = (const int*)d_in[0];
  const float* tfeat= (const float*)d_in[1];
  const float* W1   = (const float*)d_in[2];
  const float* b1   = (const float*)d_in[3];
  const float* Wa1  = (const float*)d_in[4];
  const float* ba1  = (const float*)d_in[5];
  const float* Wa2  = (const float*)d_in[6];
  const float* ba2  = (const float*)d_in[7];
  const float* Wc   = (const float*)d_in[8];
  const float* bc   = (const float*)d_in[9];
  float* out = (float*)d_out;
  (void)in_sizes; (void)n_in; (void)out_size; (void)ws_size;

  char* ws = (char*)d_ws;
  size_t off = 0;
  auto alloc = [&](size_t bytes){ void* p = ws + off; off += (bytes + 255) & ~(size_t)255; return p; };
  float* lv    = (float*)alloc((size_t)N_TOT * 4);
  float* tv    = (float*)alloc((size_t)N_TOT * 4);   // reused as w inside kselect
  float* maxlw = (float*)alloc(NUM_GROUP * 4);
  float* Zw    = (float*)alloc(NUM_GROUP * 4);
  int*   cand  = (int*)alloc(NUM_GROUP * 32 * 4);
  float* ekey  = (float*)alloc(NUM_GROUP * 32 * 4);
  float* emid  = (float*)alloc((size_t)NUM_GROUP * 32 * MDIM * 4);
  float* bagp  = (float*)alloc((size_t)NUM_GROUP * 128 * MDIM * 4);
  unsigned short* W1b  = (unsigned short*)alloc((size_t)MDIM * IN_CHN * 2);
  unsigned short* Wa1b = (unsigned short*)alloc((size_t)ATT_D * MDIM * 2);
  unsigned short* midb = (unsigned short*)alloc((size_t)N_TOT * MDIM * 2);
  float* w = tv;  // tv fully consumed inside kselect before w is written

  kconv<<<2304, 256, 0, stream>>>(W1, Wa1, W1b, Wa1b);
  kgemm_mid<<<3128, 256, 0, stream>>>(idxf, tfeat, W1b, b1, midb);
  kattn<<<782, 256, 0, stream>>>(midb, Wa1b, ba1, Wa2, ba2, Wc, lv, tv);
  kselect<<<8, 256, 0, stream>>>(lv, tv, maxlw, Zw, cand, w);
  kexact<<<256, 256, 0, stream>>>(idxf, tfeat, W1, b1, Wa1, ba1, Wa2, ba2, Wc, cand, maxlw, emid, ekey);
  kbag<<<1024, 256, 0, stream>>>(midb, w, bagp);
  kfinal<<<8, 256, 0, stream>>>(bagp, Wc, bc, emid, ekey, cand, out);
}

// Round 12
// 684.655 us; speedup vs baseline: 1.4531x; 1.0686x over previous
//
#include <hip/hip_runtime.h>
#include <stdint.h>

#define N_TOT 100000
#define IN_CHN 1024
#define MDIM 512
#define ATT_D 128
#define NUM_GROUP 8
#define GROUP_SIZE 12500
#define LDST 72  // padded LDS row stride in shorts (kattn only)
#define SEGR 98  // rows per kbag segment

typedef __bf16 bf16x8 __attribute__((ext_vector_type(8)));
typedef float f32x4 __attribute__((ext_vector_type(4)));
typedef unsigned short u16x8 __attribute__((ext_vector_type(8)));

__device__ __forceinline__ unsigned short f2bf(float x){
  union { float f; unsigned u; } v; v.f = x;
  unsigned r = v.u + 0x7fffu + ((v.u >> 16) & 1u);
  return (unsigned short)(r >> 16);
}
__device__ __forceinline__ float bf2f(unsigned short h){
  union { unsigned u; float f; } v; v.u = ((unsigned)h) << 16; return v.f;
}
__device__ __forceinline__ void gload16(const void* g, void* l){
  __builtin_amdgcn_global_load_lds(
      (const __attribute__((address_space(1))) unsigned int*)g,
      (__attribute__((address_space(3))) unsigned int*)l, 16, 0, 0);
}

// ---------------- weight conversion f32 -> bf16 ----------------
__global__ __launch_bounds__(256) void kconv(const float* __restrict__ W1,
                                             const float* __restrict__ Wa1,
                                             unsigned short* __restrict__ W1b,
                                             unsigned short* __restrict__ Wa1b){
  int i = blockIdx.x * 256 + threadIdx.x;
  if (i < MDIM * IN_CHN) W1b[i] = f2bf(W1[i]);
  else {
    int j = i - MDIM * IN_CHN;
    if (j < ATT_D * MDIM) Wa1b[j] = f2bf(Wa1[j]);
  }
}

// ---------------- main gather+GEMM: mid = relu(tfeat[idx] @ W1b^T + b1) ----------------
// 128x128 tile, K-step=64. A: f32 gathered via per-lane global_load_lds into two
// [128][32]f32 subtiles (128B rows, c^=row&7). B: bf16 [128][64] (128B rows,
// round-10-proven swizzle). 48KB LDS, 2 barriers/step. XCD-aware tile swizzle.
__global__ __launch_bounds__(256) void kgemm_mid(const int* __restrict__ idxf,
                                                 const float* __restrict__ tfeat,
                                                 const unsigned short* __restrict__ W1b,
                                                 const float* __restrict__ b1,
                                                 unsigned short* __restrict__ midb,
                                                 int base){
  __shared__ alignas(16) float Af0[128 * 32];          // 16 KB
  __shared__ alignas(16) float Af1[128 * 32];          // 16 KB
  __shared__ alignas(16) unsigned short Bsm[128 * 64]; // 16 KB
  __shared__ int gsm[128];
  int tid = threadIdx.x;
  int bidg = blockIdx.x + base;
  int tile = (bidg & 7) * 391 + (bidg >> 3);   // bijective over 0..3127
  int bn = tile & 3, bm = tile >> 2;
  int m0 = bm * 128, n0 = bn * 128;
  if (tid < 128){ int r = m0 + tid; gsm[tid] = idxf[r < N_TOT ? r : 0]; }
  __syncthreads();

  int w = tid >> 6, l = tid & 63;
  int l16 = tid & 15, hi = (tid >> 4) & 3;
  int wm = tid >> 7, wn = (tid >> 6) & 1;

  // staging sources: per round q, wave w covers rows q*32+w*8+(l>>3);
  // source chunk = (l&7)^(l>>3) so LDS(row,c) holds global chunk c^(row&7).
  const float* asrc[4];
  const unsigned short* bsrc[4];
  int adsto[4], bdsto[4];
  int scw = (l & 7) ^ (l >> 3);
  #pragma unroll
  for (int q = 0; q < 4; q++){
    int rowl = q * 32 + w * 8 + (l >> 3);
    asrc[q] = tfeat + (size_t)gsm[rowl] * IN_CHN + scw * 4;
    bsrc[q] = W1b + (size_t)(n0 + rowl) * IN_CHN + scw * 8;
    adsto[q] = (q * 32 + w * 8) * 32;
    bdsto[q] = (q * 32 + w * 8) * 64;
  }

  f32x4 acc[4][4];
  #pragma unroll
  for (int a = 0; a < 4; a++)
    #pragma unroll
    for (int b = 0; b < 4; b++) acc[a][b] = (f32x4){0.f, 0.f, 0.f, 0.f};

  int r7 = l16 & 7;

  for (int s = 0; s < 16; s++){
    __syncthreads();                 // previous compute done reading LDS
    #pragma unroll
    for (int q = 0; q < 4; q++){
      gload16(asrc[q] + s * 64,      &Af0[adsto[q]]);
      gload16(asrc[q] + s * 64 + 32, &Af1[adsto[q]]);
      gload16(bsrc[q] + s * 64,      &Bsm[bdsto[q]]);
    }
    __syncthreads();                 // drains DMA (implicit vmcnt(0))

    #pragma unroll
    for (int ks = 0; ks < 2; ks++){
      const float* At = ks ? Af1 : Af0;
      bf16x8 af[4], bfr[4];
      #pragma unroll
      for (int a = 0; a < 4; a++){
        int row = wm * 64 + a * 16 + l16;
        f32x4 lo  = *(const f32x4*)&At[row * 32 + (((2 * hi) ^ r7) << 2)];
        f32x4 hi4 = *(const f32x4*)&At[row * 32 + (((2 * hi + 1) ^ r7) << 2)];
        bf16x8 pk;
        pk[0] = (__bf16)lo[0]; pk[1] = (__bf16)lo[1]; pk[2] = (__bf16)lo[2]; pk[3] = (__bf16)lo[3];
        pk[4] = (__bf16)hi4[0]; pk[5] = (__bf16)hi4[1]; pk[6] = (__bf16)hi4[2]; pk[7] = (__bf16)hi4[3];
        af[a] = pk;
      }
      #pragma unroll
      for (int b = 0; b < 4; b++){
        int row = wn * 64 + b * 16 + l16;
        bfr[b] = *(const bf16x8*)&Bsm[row * 64 + (((ks * 4 + hi) ^ r7) << 3)];
      }
      #pragma unroll
      for (int a = 0; a < 4; a++)
        #pragma unroll
        for (int b = 0; b < 4; b++)
          acc[a][b] = __builtin_amdgcn_mfma_f32_16x16x32_bf16(af[a], bfr[b], acc[a][b], 0, 0, 0);
    }
  }

  #pragma unroll
  for (int b = 0; b < 4; b++){
    int col = n0 + wn * 64 + b * 16 + l16;
    float bias = b1[col];
    #pragma unroll
    for (int a = 0; a < 4; a++){
      int rbase = m0 + wm * 64 + a * 16 + hi * 4;
      #pragma unroll
      for (int q = 0; q < 4; q++){
        int row = rbase + q;
        if (row < N_TOT){
          float v = acc[a][b][q] + bias;
          midb[(size_t)row * MDIM + col] = f2bf(fmaxf(v, 0.f));
        }
      }
    }
  }
}

// ---------------- attention MLP + fused tv ----------------
__global__ __launch_bounds__(256) void kattn(const unsigned short* __restrict__ midb,
                                             const unsigned short* __restrict__ Wa1b,
                                             const float* __restrict__ ba1,
                                             const float* __restrict__ Wa2,
                                             const float* __restrict__ ba2,
                                             const float* __restrict__ Wc,
                                             float* __restrict__ lv,
                                             float* __restrict__ tv){
  __shared__ alignas(16) unsigned short Asm[128 * LDST];
  __shared__ alignas(16) unsigned short Bsm[128 * LDST];
  __shared__ float dsh[512];
  __shared__ float part[128][2];
  int tid = threadIdx.x;
  int m0 = blockIdx.x * 128;
  for (int i = tid; i < 512; i += 256) dsh[i] = Wc[512 + i] - Wc[i];

  int lane8 = tid & 7, rq = tid >> 3;
  const unsigned short *asrc[4], *bsrc[4];
  unsigned short *adst[4], *bdst[4];
  #pragma unroll
  for (int p = 0; p < 4; p++){
    int r = p * 32 + rq;
    int rowc = m0 + r; if (rowc > N_TOT - 1) rowc = N_TOT - 1;
    asrc[p] = midb + (size_t)rowc * MDIM + lane8 * 8;
    bsrc[p] = Wa1b + (size_t)r * MDIM + lane8 * 8;
    adst[p] = &Asm[r * LDST + lane8 * 8];
    bdst[p] = &Bsm[r * LDST + lane8 * 8];
  }
  int l16 = tid & 15, hi = (tid >> 4) & 3;
  int wm = tid >> 7, wn = (tid >> 6) & 1;
  f32x4 acc[4][4];
  #pragma unroll
  for (int a = 0; a < 4; a++)
    #pragma unroll
    for (int b = 0; b < 4; b++) acc[a][b] = (f32x4){0.f, 0.f, 0.f, 0.f};
  float tpart[4] = {0.f, 0.f, 0.f, 0.f};

  for (int s = 0; s < 8; s++){
    __syncthreads();
    #pragma unroll
    for (int p = 0; p < 4; p++){
      u16x8 av = *(const u16x8*)(asrc[p] + s * 64);
      *(u16x8*)adst[p] = av;
      *(u16x8*)bdst[p] = *(const u16x8*)(bsrc[p] + s * 64);
      #pragma unroll
      for (int e = 0; e < 8; e++)
        tpart[p] += bf2f((unsigned short)av[e]) * dsh[s * 64 + lane8 * 8 + e];
    }
    __syncthreads();
    #pragma unroll
    for (int ks = 0; ks < 2; ks++){
      int off = (ks * 4 + hi) * 8;
      bf16x8 af[4], bfr[4];
      #pragma unroll
      for (int a = 0; a < 4; a++){ int row = wm * 64 + a * 16 + l16; af[a] = *(const bf16x8*)&Asm[row * LDST + off]; }
      #pragma unroll
      for (int b = 0; b < 4; b++){ int col = wn * 64 + b * 16 + l16; bfr[b] = *(const bf16x8*)&Bsm[col * LDST + off]; }
      #pragma unroll
      for (int a = 0; a < 4; a++)
        #pragma unroll
        for (int b = 0; b < 4; b++)
          acc[a][b] = __builtin_amdgcn_mfma_f32_16x16x32_bf16(af[a], bfr[b], acc[a][b], 0, 0, 0);
    }
  }
  #pragma unroll
  for (int p = 0; p < 4; p++){
    float t = tpart[p];
    t += __shfl_xor(t, 1); t += __shfl_xor(t, 2); t += __shfl_xor(t, 4);
    if (lane8 == 0){
      int row = m0 + p * 32 + rq;
      if (row < N_TOT) tv[row] = t;
    }
  }
  #pragma unroll
  for (int a = 0; a < 4; a++){
    #pragma unroll
    for (int q = 0; q < 4; q++){
      float v = 0.f;
      #pragma unroll
      for (int b = 0; b < 4; b++){
        int col = wn * 64 + b * 16 + l16;
        v += tanhf(acc[a][b][q] + ba1[col]) * Wa2[col];
      }
      #pragma unroll
      for (int off = 1; off < 16; off <<= 1) v += __shfl_xor(v, off);
      if (l16 == 0) part[wm * 64 + a * 16 + hi * 4 + q][wn] = v;
    }
  }
  __syncthreads();
  if (tid < 128){
    int row = m0 + tid;
    if (row < N_TOT) lv[row] = part[tid][0] + part[tid][1] + ba2[0];
  }
}

// ---------------- per-group stats + top/bottom-16 + fused softmax weights ----------------
// local per-thread reg top-16 (static bubble) -> 4096 LDS candidates -> 16 argmax iters
__global__ __launch_bounds__(256) void kselect(const float* __restrict__ lv,
                                               const float* __restrict__ tv,
                                               float* __restrict__ maxlw, float* __restrict__ Zw,
                                               int* __restrict__ cand,
                                               float* __restrict__ w){
  __shared__ float keys[GROUP_SIZE];
  __shared__ float candk[4096];
  __shared__ int   candi[4096];
  __shared__ float rk[256];
  __shared__ int ri[256];
  __shared__ int rs[256];
  __shared__ float sbc;
  int g = blockIdx.x, tid = threadIdx.x;
  const float* lg = lv + (size_t)g * GROUP_SIZE;
  const float* tg = tv + (size_t)g * GROUP_SIZE;

  float mx = -1e30f;
  for (int i = tid; i < GROUP_SIZE; i += 256) mx = fmaxf(mx, lg[i]);
  rk[tid] = mx; __syncthreads();
  for (int s = 128; s > 0; s >>= 1){ if (tid < s) rk[tid] = fmaxf(rk[tid], rk[tid + s]); __syncthreads(); }
  if (tid == 0) sbc = rk[0];
  __syncthreads();
  float maxl = sbc;

  float z = 0.f;
  for (int i = tid; i < GROUP_SIZE; i += 256){
    float ez = expf(lg[i] - maxl);
    z += ez;
    keys[i] = ez * tg[i];
  }
  rk[tid] = z; __syncthreads();
  for (int s = 128; s > 0; s >>= 1){ if (tid < s) rk[tid] += rk[tid + s]; __syncthreads(); }
  if (tid == 0){ maxlw[g] = maxl; Zw[g] = rk[0]; }
  __syncthreads();
  float invZ = 1.0f / rk[0];
  for (int i = tid; i < GROUP_SIZE; i += 256)
    w[(size_t)g * GROUP_SIZE + i] = expf(lg[i] - maxl) * invZ;
  __syncthreads();

  // ---- TOP-16 ----
  {
    float tk[16]; int tix[16];
    #pragma unroll
    for (int j = 0; j < 16; j++){ tk[j] = -1e30f; tix[j] = 0x7fffffff; }
    for (int i = tid; i < GROUP_SIZE; i += 256){
      float ck = keys[i];
      if (ck > tk[15]){
        int ci = i;
        #pragma unroll
        for (int j = 0; j < 16; j++){
          bool ins = ck > tk[j];
          float nk = ins ? ck : tk[j]; int ni = ins ? ci : tix[j];
          float ok = ins ? tk[j] : ck; int oi = ins ? tix[j] : ci;
          tk[j] = nk; tix[j] = ni; ck = ok; ci = oi;
        }
      }
    }
    #pragma unroll
    for (int j = 0; j < 16; j++){ candk[tid * 16 + j] = tk[j]; candi[tid * 16 + j] = tix[j]; }
  }
  __syncthreads();
  for (int it = 0; it < 16; it++){
    float bk = -1e30f; int bi = 0x7fffffff; int bs = -1;
    for (int jj = tid; jj < 4096; jj += 256){
      float k = candk[jj]; int ix = candi[jj];
      if (k > bk || (k == bk && ix < bi)){ bk = k; bi = ix; bs = jj; }
    }
    rk[tid] = bk; ri[tid] = bi; rs[tid] = bs; __syncthreads();
    for (int s = 128; s > 0; s >>= 1){
      if (tid < s){
        if (rk[tid + s] > rk[tid] || (rk[tid + s] == rk[tid] && ri[tid + s] < ri[tid])){
          rk[tid] = rk[tid + s]; ri[tid] = ri[tid + s]; rs[tid] = rs[tid + s];
        }
      }
      __syncthreads();
    }
    if (tid == 0){ cand[g * 32 + it] = ri[0]; candk[rs[0]] = -1e30f; }
    __syncthreads();
  }

  // ---- BOTTOM-16 ----
  {
    float tk[16]; int tix[16];
    #pragma unroll
    for (int j = 0; j < 16; j++){ tk[j] = 1e30f; tix[j] = -1; }
    for (int i = tid; i < GROUP_SIZE; i += 256){
      float ck = keys[i];
      if (ck <= tk[15]){
        int ci = i;
        #pragma unroll
        for (int j = 0; j < 16; j++){
          bool ins = ck <= tk[j];   // ties: later (larger) idx goes first
          float nk = ins ? ck : tk[j]; int ni = ins ? ci : tix[j];
          float ok = ins ? tk[j] : ck; int oi = ins ? tix[j] : ci;
          tk[j] = nk; tix[j] = ni; ck = ok; ci = oi;
        }
      }
    }
    #pragma unroll
    for (int j = 0; j < 16; j++){ candk[tid * 16 + j] = tk[j]; candi[tid * 16 + j] = tix[j]; }
  }
  __syncthreads();
  for (int it = 0; it < 16; it++){
    float bk = 1e30f; int bi = -1; int bs = -1;
    for (int jj = tid; jj < 4096; jj += 256){
      float k = candk[jj]; int ix = candi[jj];
      if (k < bk || (k == bk && ix > bi)){ bk = k; bi = ix; bs = jj; }
    }
    rk[tid] = bk; ri[tid] = bi; rs[tid] = bs; __syncthreads();
    for (int s = 128; s > 0; s >>= 1){
      if (tid < s){
        if (rk[tid + s] < rk[tid] || (rk[tid + s] == rk[tid] && ri[tid + s] > ri[tid])){
          rk[tid] = rk[tid + s]; ri[tid] = ri[tid + s]; rs[tid] = rs[tid + s];
        }
      }
      __syncthreads();
    }
    if (tid == 0){ cand[g * 32 + 16 + it] = ri[0]; candk[rs[0]] = 1e30f; }
    __syncthreads();
  }
}

// ---------------- exact f32 recompute of 256 candidate rows ----------------
__global__ __launch_bounds__(256) void kexact(const int* __restrict__ idxf,
                                              const float* __restrict__ tfeat,
                                              const float* __restrict__ W1,
                                              const float* __restrict__ b1,
                                              const float* __restrict__ Wa1,
                                              const float* __restrict__ ba1,
                                              const float* __restrict__ Wa2,
                                              const float* __restrict__ ba2,
                                              const float* __restrict__ Wc,
                                              const int* __restrict__ cand,
                                              const float* __restrict__ maxlw,
                                              float* __restrict__ emid, float* __restrict__ ekey){
  __shared__ float subs[1024];
  __shared__ float midc[512];
  __shared__ float hs[128];
  __shared__ float red[256];
  __shared__ float tsh;
  int bid = blockIdx.x; int g = bid >> 5, c = bid & 31; int tid = threadIdx.x;
  int s = cand[g * 32 + c];
  int inst = idxf[g * GROUP_SIZE + s];
  ((float4*)subs)[tid] = ((const float4*)(tfeat + (size_t)inst * IN_CHN))[tid];
  __syncthreads();

  float a0 = b1[tid], a1 = b1[tid + 256];
  const float4* w0 = (const float4*)(W1 + (size_t)tid * IN_CHN);
  const float4* w1 = (const float4*)(W1 + ((size_t)tid + 256) * IN_CHN);
  const float4* s4 = (const float4*)subs;
  #pragma unroll 4
  for (int k = 0; k < 256; k++){
    float4 sv = s4[k], wva = w0[k], wvb = w1[k];
    a0 += sv.x * wva.x + sv.y * wva.y + sv.z * wva.z + sv.w * wva.w;
    a1 += sv.x * wvb.x + sv.y * wvb.y + sv.z * wvb.z + sv.w * wvb.w;
  }
  a0 = fmaxf(a0, 0.f); a1 = fmaxf(a1, 0.f);
  midc[tid] = a0; midc[tid + 256] = a1;
  size_t eo = (size_t)(g * 32 + c) * MDIM;
  emid[eo + tid] = a0; emid[eo + tid + 256] = a1;
  __syncthreads();

  if (tid < 128){
    const float4* wr = (const float4*)(Wa1 + (size_t)tid * MDIM);
    const float4* m4 = (const float4*)midc;
    float h = ba1[tid];
    #pragma unroll 4
    for (int j = 0; j < 128; j++){
      float4 mv = m4[j], wv = wr[j];
      h += mv.x * wv.x + mv.y * wv.y + mv.z * wv.z + mv.w * wv.w;
    }
    hs[tid] = tanhf(h) * Wa2[tid];
  }
  __syncthreads();

  float tp = midc[tid] * (Wc[512 + tid] - Wc[tid]) + midc[tid + 256] * (Wc[768 + tid] - Wc[256 + tid]);
  red[tid] = tp; __syncthreads();
  for (int st = 128; st > 0; st >>= 1){ if (tid < st) red[tid] += red[tid + st]; __syncthreads(); }
  if (tid == 0) tsh = red[0];
  __syncthreads();
  red[tid] = (tid < 128) ? hs[tid] : 0.f; __syncthreads();
  for (int st = 128; st > 0; st >>= 1){ if (tid < st) red[tid] += red[tid + st]; __syncthreads(); }
  if (tid == 0){
    float lval = red[0] + ba2[0];
    ekey[g * 32 + c] = expf(lval - maxlw[g]) * tsh;
  }
}

// ---------------- weighted bag-sum: 128 segments x 8 groups, partials ----------------
__global__ __launch_bounds__(256) void kbag(const unsigned short* __restrict__ midb,
                                            const float* __restrict__ w,
                                            float* __restrict__ bagp){
  __shared__ float wl[SEGR];
  int g = blockIdx.x >> 7, seg = blockIdx.x & 127, tid = threadIdx.x;
  int i0 = seg * SEGR;
  int nr = GROUP_SIZE - i0; if (nr > SEGR) nr = SEGR;
  size_t base = (size_t)g * GROUP_SIZE;
  if (tid < nr) wl[tid] = w[base + i0 + tid];
  __syncthreads();
  float a0 = 0.f, a1 = 0.f;
  const unsigned short* mp = midb + (base + i0) * MDIM + 2 * tid;
  int i = 0;
  for (; i + 2 <= nr; i += 2){
    unsigned pk0 = *(const unsigned*)(mp + (size_t)i * MDIM);
    unsigned pk1 = *(const unsigned*)(mp + (size_t)(i + 1) * MDIM);
    float w0 = wl[i], w1 = wl[i + 1];
    a0 += w0 * bf2f((unsigned short)(pk0 & 0xffff)) + w1 * bf2f((unsigned short)(pk1 & 0xffff));
    a1 += w0 * bf2f((unsigned short)(pk0 >> 16)) + w1 * bf2f((unsigned short)(pk1 >> 16));
  }
  if (i < nr){
    unsigned pk0 = *(const unsigned*)(mp + (size_t)i * MDIM);
    float w0 = wl[i];
    a0 += w0 * bf2f((unsigned short)(pk0 & 0xffff));
    a1 += w0 * bf2f((unsigned short)(pk0 >> 16));
  }
  float* dst = bagp + (size_t)blockIdx.x * MDIM + 2 * tid;
  dst[0] = a0; dst[1] = a1;
}

// ---------------- final: exact re-rank, preds, feature copy — FLOAT32 output ----------------
__global__ __launch_bounds__(256) void kfinal(const float* __restrict__ bagp,
                                              const float* __restrict__ Wc,
                                              const float* __restrict__ bc,
                                              const float* __restrict__ emid,
                                              const float* __restrict__ ekey,
                                              const int* __restrict__ cand,
                                              float* __restrict__ out){
  __shared__ float k32[32];
  __shared__ int s32[32];
  __shared__ int ordv[32];
  __shared__ float r0[256], r1[256];
  int g = blockIdx.x, tid = threadIdx.x;
  if (tid < 32){ k32[tid] = ekey[g * 32 + tid]; s32[tid] = cand[g * 32 + tid]; }
  __syncthreads();
  if (tid == 0){
    unsigned used = 0;
    for (int a = 0; a < 32; a++){
      int best = -1;
      for (int b = 0; b < 32; b++){
        if ((used >> b) & 1u) continue;
        if (best < 0 || k32[b] > k32[best] || (k32[b] == k32[best] && s32[b] < s32[best])) best = b;
      }
      used |= 1u << best;
      ordv[a] = best;
    }
  }
  float p0 = 0.f, p1 = 0.f;
  for (int j = tid; j < 512; j += 256){
    float bv = 0.f;
    for (int s2 = 0; s2 < 128; s2++) bv += bagp[(size_t)(g * 128 + s2) * MDIM + j];
    p0 += bv * Wc[j];
    p1 += bv * Wc[512 + j];
  }
  r0[tid] = p0; r1[tid] = p1; __syncthreads();
  for (int s = 128; s > 0; s >>= 1){ if (tid < s){ r0[tid] += r0[tid + s]; r1[tid] += r1[tid + s]; } __syncthreads(); }
  if (tid == 0){
    out[g * 2 + 0] = r0[0] + bc[0];
    out[g * 2 + 1] = r1[0] + bc[1];
  }
  __syncthreads();
  for (int p = 0; p < 8; p++){
    int cc = ordv[p < 4 ? p : 24 + p];
    const float* src = emid + (size_t)(g * 32 + cc) * MDIM;
    float* dst = out + 16 + (size_t)(g * 8 + p) * MDIM;
    for (int j = tid; j < 512; j += 256) dst[j] = src[j];
  }
}

extern "C" void kernel_launch(void* const* d_in, const int* in_sizes, int n_in,
                              void* d_out, int out_size, void* d_ws, size_t ws_size,
                              hipStream_t stream){
  const int*   idxf = (const int*)d_in[0];
  const float* tfeat= (const float*)d_in[1];
  const float* W1   = (const float*)d_in[2];
  const float* b1   = (const float*)d_in[3];
  const float* Wa1  = (const float*)d_in[4];
  const float* ba1  = (const float*)d_in[5];
  const float* Wa2  = (const float*)d_in[6];
  const float* ba2  = (const float*)d_in[7];
  const float* Wc   = (const float*)d_in[8];
  const float* bc   = (const float*)d_in[9];
  float* out = (float*)d_out;
  (void)in_sizes; (void)n_in; (void)out_size; (void)ws_size;

  char* ws = (char*)d_ws;
  size_t off = 0;
  auto alloc = [&](size_t bytes){ void* p = ws + off; off += (bytes + 255) & ~(size_t)255; return p; };
  float* lv    = (float*)alloc((size_t)N_TOT * 4);
  float* tv    = (float*)alloc((size_t)N_TOT * 4);   // reused as w inside kselect
  float* maxlw = (float*)alloc(NUM_GROUP * 4);
  float* Zw    = (float*)alloc(NUM_GROUP * 4);
  int*   cand  = (int*)alloc(NUM_GROUP * 32 * 4);
  float* ekey  = (float*)alloc(NUM_GROUP * 32 * 4);
  float* emid  = (float*)alloc((size_t)NUM_GROUP * 32 * MDIM * 4);
  float* bagp  = (float*)alloc((size_t)NUM_GROUP * 128 * MDIM * 4);
  unsigned short* W1b  = (unsigned short*)alloc((size_t)MDIM * IN_CHN * 2);
  unsigned short* Wa1b = (unsigned short*)alloc((size_t)ATT_D * MDIM * 2);
  unsigned short* midb = (unsigned short*)alloc((size_t)N_TOT * MDIM * 2);
  float* w = tv;  // tv fully consumed inside kselect before w is written

  kconv<<<2304, 256, 0, stream>>>(W1, Wa1, W1b, Wa1b);
  kgemm_mid<<<1564, 256, 0, stream>>>(idxf, tfeat, W1b, b1, midb, 0);
  kgemm_mid<<<1564, 256, 0, stream>>>(idxf, tfeat, W1b, b1, midb, 1564);
  kattn<<<782, 256, 0, stream>>>(midb, Wa1b, ba1, Wa2, ba2, Wc, lv, tv);
  kselect<<<8, 256, 0, stream>>>(lv, tv, maxlw, Zw, cand, w);
  kexact<<<256, 256, 0, stream>>>(idxf, tfeat, W1, b1, Wa1, ba1, Wa2, ba2, Wc, cand, maxlw, emid, ekey);
  kbag<<<1024, 256, 0, stream>>>(midb, w, bagp);
  kfinal<<<8, 256, 0, stream>>>(bagp, Wc, bc, emid, ekey, cand, out);
}

// Round 13
// 656.822 us; speedup vs baseline: 1.5147x; 1.0424x over previous
//
#include <hip/hip_runtime.h>
#include <stdint.h>

#define N_TOT 100000
#define IN_CHN 1024
#define MDIM 512
#define ATT_D 128
#define NUM_GROUP 8
#define GROUP_SIZE 12500
#define SEGR 98  // rows per kbag segment

typedef __bf16 bf16x8 __attribute__((ext_vector_type(8)));
typedef float f32x4 __attribute__((ext_vector_type(4)));
typedef unsigned short u16x8 __attribute__((ext_vector_type(8)));

__device__ __forceinline__ unsigned short f2bf(float x){
  union { float f; unsigned u; } v; v.f = x;
  unsigned r = v.u + 0x7fffu + ((v.u >> 16) & 1u);
  return (unsigned short)(r >> 16);
}
__device__ __forceinline__ float bf2f(unsigned short h){
  union { unsigned u; float f; } v; v.u = ((unsigned)h) << 16; return v.f;
}
__device__ __forceinline__ void gload16(const void* g, void* l){
  __builtin_amdgcn_global_load_lds(
      (const __attribute__((address_space(1))) unsigned int*)g,
      (__attribute__((address_space(3))) unsigned int*)l, 16, 0, 0);
}

// ---------------- weight conversion f32 -> bf16 ----------------
__global__ __launch_bounds__(256) void kconv(const float* __restrict__ W1,
                                             const float* __restrict__ Wa1,
                                             unsigned short* __restrict__ W1b,
                                             unsigned short* __restrict__ Wa1b){
  int i = blockIdx.x * 256 + threadIdx.x;
  if (i < MDIM * IN_CHN) W1b[i] = f2bf(W1[i]);
  else {
    int j = i - MDIM * IN_CHN;
    if (j < ATT_D * MDIM) Wa1b[j] = f2bf(Wa1[j]);
  }
}

// ---------------- main gather+GEMM: mid = relu(tfeat[idx] @ W1b^T + b1) ----------------
// 128x128 tile, K-step=64. A: f32 gathered via per-lane global_load_lds into two
// [128][32]f32 subtiles (128B rows, c^=row&7). B: bf16 [128][64] (128B rows,
// round-10-proven swizzle). 48KB LDS, 2 barriers/step. XCD-aware tile swizzle.
__global__ __launch_bounds__(256) void kgemm_mid(const int* __restrict__ idxf,
                                                 const float* __restrict__ tfeat,
                                                 const unsigned short* __restrict__ W1b,
                                                 const float* __restrict__ b1,
                                                 unsigned short* __restrict__ midb){
  __shared__ alignas(16) float Af0[128 * 32];          // 16 KB
  __shared__ alignas(16) float Af1[128 * 32];          // 16 KB
  __shared__ alignas(16) unsigned short Bsm[128 * 64]; // 16 KB
  __shared__ int gsm[128];
  int tid = threadIdx.x;
  int bidg = blockIdx.x;
  int tile = (bidg & 7) * 391 + (bidg >> 3);   // bijective over 0..3127
  int bn = tile & 3, bm = tile >> 2;
  int m0 = bm * 128, n0 = bn * 128;
  if (tid < 128){ int r = m0 + tid; gsm[tid] = idxf[r < N_TOT ? r : 0]; }
  __syncthreads();

  int w = tid >> 6, l = tid & 63;
  int l16 = tid & 15, hi = (tid >> 4) & 3;
  int wm = tid >> 7, wn = (tid >> 6) & 1;

  const float* asrc[4];
  const unsigned short* bsrc[4];
  int adsto[4], bdsto[4];
  int scw = (l & 7) ^ (l >> 3);
  #pragma unroll
  for (int q = 0; q < 4; q++){
    int rowl = q * 32 + w * 8 + (l >> 3);
    asrc[q] = tfeat + (size_t)gsm[rowl] * IN_CHN + scw * 4;
    bsrc[q] = W1b + (size_t)(n0 + rowl) * IN_CHN + scw * 8;
    adsto[q] = (q * 32 + w * 8) * 32;
    bdsto[q] = (q * 32 + w * 8) * 64;
  }

  f32x4 acc[4][4];
  #pragma unroll
  for (int a = 0; a < 4; a++)
    #pragma unroll
    for (int b = 0; b < 4; b++) acc[a][b] = (f32x4){0.f, 0.f, 0.f, 0.f};

  int r7 = l16 & 7;

  for (int s = 0; s < 16; s++){
    __syncthreads();
    #pragma unroll
    for (int q = 0; q < 4; q++){
      gload16(asrc[q] + s * 64,      &Af0[adsto[q]]);
      gload16(asrc[q] + s * 64 + 32, &Af1[adsto[q]]);
      gload16(bsrc[q] + s * 64,      &Bsm[bdsto[q]]);
    }
    __syncthreads();

    #pragma unroll
    for (int ks = 0; ks < 2; ks++){
      const float* At = ks ? Af1 : Af0;
      bf16x8 af[4], bfr[4];
      #pragma unroll
      for (int a = 0; a < 4; a++){
        int row = wm * 64 + a * 16 + l16;
        f32x4 lo  = *(const f32x4*)&At[row * 32 + (((2 * hi) ^ r7) << 2)];
        f32x4 hi4 = *(const f32x4*)&At[row * 32 + (((2 * hi + 1) ^ r7) << 2)];
        bf16x8 pk;
        pk[0] = (__bf16)lo[0]; pk[1] = (__bf16)lo[1]; pk[2] = (__bf16)lo[2]; pk[3] = (__bf16)lo[3];
        pk[4] = (__bf16)hi4[0]; pk[5] = (__bf16)hi4[1]; pk[6] = (__bf16)hi4[2]; pk[7] = (__bf16)hi4[3];
        af[a] = pk;
      }
      #pragma unroll
      for (int b = 0; b < 4; b++){
        int row = wn * 64 + b * 16 + l16;
        bfr[b] = *(const bf16x8*)&Bsm[row * 64 + (((ks * 4 + hi) ^ r7) << 3)];
      }
      #pragma unroll
      for (int a = 0; a < 4; a++)
        #pragma unroll
        for (int b = 0; b < 4; b++)
          acc[a][b] = __builtin_amdgcn_mfma_f32_16x16x32_bf16(af[a], bfr[b], acc[a][b], 0, 0, 0);
    }
  }

  #pragma unroll
  for (int b = 0; b < 4; b++){
    int col = n0 + wn * 64 + b * 16 + l16;
    float bias = b1[col];
    #pragma unroll
    for (int a = 0; a < 4; a++){
      int rbase = m0 + wm * 64 + a * 16 + hi * 4;
      #pragma unroll
      for (int q = 0; q < 4; q++){
        int row = rbase + q;
        if (row < N_TOT){
          float v = acc[a][b][q] + bias;
          midb[(size_t)row * MDIM + col] = f2bf(fmaxf(v, 0.f));
        }
      }
    }
  }
}

// ---------------- attention MLP + fused tv: gload_lds staging, proven swizzle ----------------
// lv = tanh(mid@Wa1^T+ba1)@Wa2+ba2 ; tv = mid.(Wc1-Wc0)
__global__ __launch_bounds__(256) void kattn(const unsigned short* __restrict__ midb,
                                             const unsigned short* __restrict__ Wa1b,
                                             const float* __restrict__ ba1,
                                             const float* __restrict__ Wa2,
                                             const float* __restrict__ ba2,
                                             const float* __restrict__ Wc,
                                             float* __restrict__ lv,
                                             float* __restrict__ tv){
  __shared__ alignas(16) unsigned short Asm[128 * 64];  // mid rows tile, 16 KB
  __shared__ alignas(16) unsigned short Bsm[128 * 64];  // Wa1 rows tile, 16 KB
  __shared__ float dsh[512];
  __shared__ float part[128][2];
  int tid = threadIdx.x;
  int m0 = blockIdx.x * 128;
  for (int i = tid; i < 512; i += 256) dsh[i] = Wc[512 + i] - Wc[i];

  int w = tid >> 6, l = tid & 63;
  int l16 = tid & 15, hi = (tid >> 4) & 3;
  int wm = tid >> 7, wn = (tid >> 6) & 1;
  int scw = (l & 7) ^ (l >> 3);

  const unsigned short *asrc[4], *bsrc[4];
  int dsto[4];
  #pragma unroll
  for (int q = 0; q < 4; q++){
    int rowl = q * 32 + w * 8 + (l >> 3);
    asrc[q] = midb + (size_t)(m0 + rowl) * MDIM + scw * 8;  // OOB rows: ws garbage, rows don't mix
    bsrc[q] = Wa1b + (size_t)rowl * MDIM + scw * 8;          // rowl < 128 = ATT_D
    dsto[q] = (q * 32 + w * 8) * 64;
  }

  f32x4 acc[4][4];
  #pragma unroll
  for (int a = 0; a < 4; a++)
    #pragma unroll
    for (int b = 0; b < 4; b++) acc[a][b] = (f32x4){0.f, 0.f, 0.f, 0.f};
  int r7 = l16 & 7;

  // tv accumulation geometry: row rt=tid>>1 (0..127), half kh=tid&1 (global chunks kh*4..kh*4+3)
  int rt = tid >> 1, kh = tid & 1;
  int rt7 = rt & 7;
  float t = 0.f;

  for (int s = 0; s < 8; s++){
    __syncthreads();
    #pragma unroll
    for (int q = 0; q < 4; q++){
      gload16(asrc[q] + s * 64, &Asm[dsto[q]]);
      gload16(bsrc[q] + s * 64, &Bsm[dsto[q]]);
    }
    __syncthreads();
    // MFMA
    #pragma unroll
    for (int ks = 0; ks < 2; ks++){
      bf16x8 af[4], bfr[4];
      #pragma unroll
      for (int a = 0; a < 4; a++){
        int row = wm * 64 + a * 16 + l16;
        af[a] = *(const bf16x8*)&Asm[row * 64 + (((ks * 4 + hi) ^ r7) << 3)];
      }
      #pragma unroll
      for (int b = 0; b < 4; b++){
        int row = wn * 64 + b * 16 + l16;
        bfr[b] = *(const bf16x8*)&Bsm[row * 64 + (((ks * 4 + hi) ^ r7) << 3)];
      }
      #pragma unroll
      for (int a = 0; a < 4; a++)
        #pragma unroll
        for (int b = 0; b < 4; b++)
          acc[a][b] = __builtin_amdgcn_mfma_f32_16x16x32_bf16(af[a], bfr[b], acc[a][b], 0, 0, 0);
    }
    // tv partial from the A tile (swizzled, bank-balanced reads)
    #pragma unroll
    for (int j = 0; j < 4; j++){
      int gc = kh * 4 + j;
      u16x8 v = *(const u16x8*)&Asm[rt * 64 + ((gc ^ rt7) << 3)];
      int kb = s * 64 + gc * 8;
      #pragma unroll
      for (int e = 0; e < 8; e++) t += bf2f((unsigned short)v[e]) * dsh[kb + e];
    }
  }
  t += __shfl_xor(t, 1);
  if (kh == 0){
    int row = m0 + rt;
    if (row < N_TOT) tv[row] = t;
  }
  // lv epilogue
  #pragma unroll
  for (int a = 0; a < 4; a++){
    #pragma unroll
    for (int q = 0; q < 4; q++){
      float v = 0.f;
      #pragma unroll
      for (int b = 0; b < 4; b++){
        int col = wn * 64 + b * 16 + l16;
        v += tanhf(acc[a][b][q] + ba1[col]) * Wa2[col];
      }
      #pragma unroll
      for (int off = 1; off < 16; off <<= 1) v += __shfl_xor(v, off);
      if (l16 == 0) part[wm * 64 + a * 16 + hi * 4 + q][wn] = v;
    }
  }
  __syncthreads();
  if (tid < 128){
    int row = m0 + tid;
    if (row < N_TOT) lv[row] = part[tid][0] + part[tid][1] + ba2[0];
  }
}

// ---------------- per-group stats + top/bottom-16 + fused softmax weights ----------------
__global__ __launch_bounds__(256) void kselect(const float* __restrict__ lv,
                                               const float* __restrict__ tv,
                                               float* __restrict__ maxlw, float* __restrict__ Zw,
                                               int* __restrict__ cand,
                                               float* __restrict__ w){
  __shared__ float keys[GROUP_SIZE];
  __shared__ float candk[4096];
  __shared__ int   candi[4096];
  __shared__ float rk[256];
  __shared__ int ri[256];
  __shared__ int rs[256];
  __shared__ float sbc;
  int g = blockIdx.x, tid = threadIdx.x;
  const float* lg = lv + (size_t)g * GROUP_SIZE;
  const float* tg = tv + (size_t)g * GROUP_SIZE;

  float mx = -1e30f;
  for (int i = tid; i < GROUP_SIZE; i += 256) mx = fmaxf(mx, lg[i]);
  rk[tid] = mx; __syncthreads();
  for (int s = 128; s > 0; s >>= 1){ if (tid < s) rk[tid] = fmaxf(rk[tid], rk[tid + s]); __syncthreads(); }
  if (tid == 0) sbc = rk[0];
  __syncthreads();
  float maxl = sbc;

  float z = 0.f;
  for (int i = tid; i < GROUP_SIZE; i += 256){
    float ez = expf(lg[i] - maxl);
    z += ez;
    keys[i] = ez * tg[i];
  }
  rk[tid] = z; __syncthreads();
  for (int s = 128; s > 0; s >>= 1){ if (tid < s) rk[tid] += rk[tid + s]; __syncthreads(); }
  if (tid == 0){ maxlw[g] = maxl; Zw[g] = rk[0]; }
  __syncthreads();
  float invZ = 1.0f / rk[0];
  for (int i = tid; i < GROUP_SIZE; i += 256)
    w[(size_t)g * GROUP_SIZE + i] = expf(lg[i] - maxl) * invZ;
  __syncthreads();

  // ---- TOP-16 ----
  {
    float tk[16]; int tix[16];
    #pragma unroll
    for (int j = 0; j < 16; j++){ tk[j] = -1e30f; tix[j] = 0x7fffffff; }
    for (int i = tid; i < GROUP_SIZE; i += 256){
      float ck = keys[i];
      if (ck > tk[15]){
        int ci = i;
        #pragma unroll
        for (int j = 0; j < 16; j++){
          bool ins = ck > tk[j];
          float nk = ins ? ck : tk[j]; int ni = ins ? ci : tix[j];
          float ok = ins ? tk[j] : ck; int oi = ins ? tix[j] : ci;
          tk[j] = nk; tix[j] = ni; ck = ok; ci = oi;
        }
      }
    }
    #pragma unroll
    for (int j = 0; j < 16; j++){ candk[tid * 16 + j] = tk[j]; candi[tid * 16 + j] = tix[j]; }
  }
  __syncthreads();
  for (int it = 0; it < 16; it++){
    float bk = -1e30f; int bi = 0x7fffffff; int bs = -1;
    for (int jj = tid; jj < 4096; jj += 256){
      float k = candk[jj]; int ix = candi[jj];
      if (k > bk || (k == bk && ix < bi)){ bk = k; bi = ix; bs = jj; }
    }
    rk[tid] = bk; ri[tid] = bi; rs[tid] = bs; __syncthreads();
    for (int s = 128; s > 0; s >>= 1){
      if (tid < s){
        if (rk[tid + s] > rk[tid] || (rk[tid + s] == rk[tid] && ri[tid + s] < ri[tid])){
          rk[tid] = rk[tid + s]; ri[tid] = ri[tid + s]; rs[tid] = rs[tid + s];
        }
      }
      __syncthreads();
    }
    if (tid == 0){ cand[g * 32 + it] = ri[0]; candk[rs[0]] = -1e30f; }
    __syncthreads();
  }

  // ---- BOTTOM-16 ----
  {
    float tk[16]; int tix[16];
    #pragma unroll
    for (int j = 0; j < 16; j++){ tk[j] = 1e30f; tix[j] = -1; }
    for (int i = tid; i < GROUP_SIZE; i += 256){
      float ck = keys[i];
      if (ck <= tk[15]){
        int ci = i;
        #pragma unroll
        for (int j = 0; j < 16; j++){
          bool ins = ck <= tk[j];   // ties: later (larger) idx goes first
          float nk = ins ? ck : tk[j]; int ni = ins ? ci : tix[j];
          float ok = ins ? tk[j] : ck; int oi = ins ? tix[j] : ci;
          tk[j] = nk; tix[j] = ni; ck = ok; ci = oi;
        }
      }
    }
    #pragma unroll
    for (int j = 0; j < 16; j++){ candk[tid * 16 + j] = tk[j]; candi[tid * 16 + j] = tix[j]; }
  }
  __syncthreads();
  for (int it = 0; it < 16; it++){
    float bk = 1e30f; int bi = -1; int bs = -1;
    for (int jj = tid; jj < 4096; jj += 256){
      float k = candk[jj]; int ix = candi[jj];
      if (k < bk || (k == bk && ix > bi)){ bk = k; bi = ix; bs = jj; }
    }
    rk[tid] = bk; ri[tid] = bi; rs[tid] = bs; __syncthreads();
    for (int s = 128; s > 0; s >>= 1){
      if (tid < s){
        if (rk[tid + s] < rk[tid] || (rk[tid + s] == rk[tid] && ri[tid + s] > ri[tid])){
          rk[tid] = rk[tid + s]; ri[tid] = ri[tid + s]; rs[tid] = rs[tid + s];
        }
      }
      __syncthreads();
    }
    if (tid == 0){ cand[g * 32 + 16 + it] = ri[0]; candk[rs[0]] = 1e30f; }
    __syncthreads();
  }
}

// ---------------- exact f32 recompute of 256 candidate rows ----------------
__global__ __launch_bounds__(256) void kexact(const int* __restrict__ idxf,
                                              const float* __restrict__ tfeat,
                                              const float* __restrict__ W1,
                                              const float* __restrict__ b1,
                                              const float* __restrict__ Wa1,
                                              const float* __restrict__ ba1,
                                              const float* __restrict__ Wa2,
                                              const float* __restrict__ ba2,
                                              const float* __restrict__ Wc,
                                              const int* __restrict__ cand,
                                              const float* __restrict__ maxlw,
                                              float* __restrict__ emid, float* __restrict__ ekey){
  __shared__ float subs[1024];
  __shared__ float midc[512];
  __shared__ float hs[128];
  __shared__ float red[256];
  __shared__ float tsh;
  int bid = blockIdx.x; int g = bid >> 5, c = bid & 31; int tid = threadIdx.x;
  int s = cand[g * 32 + c];
  int inst = idxf[g * GROUP_SIZE + s];
  ((float4*)subs)[tid] = ((const float4*)(tfeat + (size_t)inst * IN_CHN))[tid];
  __syncthreads();

  float a0 = b1[tid], a1 = b1[tid + 256];
  const float4* w0 = (const float4*)(W1 + (size_t)tid * IN_CHN);
  const float4* w1 = (const float4*)(W1 + ((size_t)tid + 256) * IN_CHN);
  const float4* s4 = (const float4*)subs;
  #pragma unroll 4
  for (int k = 0; k < 256; k++){
    float4 sv = s4[k], wva = w0[k], wvb = w1[k];
    a0 += sv.x * wva.x + sv.y * wva.y + sv.z * wva.z + sv.w * wva.w;
    a1 += sv.x * wvb.x + sv.y * wvb.y + sv.z * wvb.z + sv.w * wvb.w;
  }
  a0 = fmaxf(a0, 0.f); a1 = fmaxf(a1, 0.f);
  midc[tid] = a0; midc[tid + 256] = a1;
  size_t eo = (size_t)(g * 32 + c) * MDIM;
  emid[eo + tid] = a0; emid[eo + tid + 256] = a1;
  __syncthreads();

  if (tid < 128){
    const float4* wr = (const float4*)(Wa1 + (size_t)tid * MDIM);
    const float4* m4 = (const float4*)midc;
    float h = ba1[tid];
    #pragma unroll 4
    for (int j = 0; j < 128; j++){
      float4 mv = m4[j], wv = wr[j];
      h += mv.x * wv.x + mv.y * wv.y + mv.z * wv.z + mv.w * wv.w;
    }
    hs[tid] = tanhf(h) * Wa2[tid];
  }
  __syncthreads();

  float tp = midc[tid] * (Wc[512 + tid] - Wc[tid]) + midc[tid + 256] * (Wc[768 + tid] - Wc[256 + tid]);
  red[tid] = tp; __syncthreads();
  for (int st = 128; st > 0; st >>= 1){ if (tid < st) red[tid] += red[tid + st]; __syncthreads(); }
  if (tid == 0) tsh = red[0];
  __syncthreads();
  red[tid] = (tid < 128) ? hs[tid] : 0.f; __syncthreads();
  for (int st = 128; st > 0; st >>= 1){ if (tid < st) red[tid] += red[tid + st]; __syncthreads(); }
  if (tid == 0){
    float lval = red[0] + ba2[0];
    ekey[g * 32 + c] = expf(lval - maxlw[g]) * tsh;
  }
}

// ---------------- weighted bag-sum: 128 segments x 8 groups, partials ----------------
__global__ __launch_bounds__(256) void kbag(const unsigned short* __restrict__ midb,
                                            const float* __restrict__ w,
                                            float* __restrict__ bagp){
  __shared__ float wl[SEGR];
  int g = blockIdx.x >> 7, seg = blockIdx.x & 127, tid = threadIdx.x;
  int i0 = seg * SEGR;
  int nr = GROUP_SIZE - i0; if (nr > SEGR) nr = SEGR;
  size_t base = (size_t)g * GROUP_SIZE;
  if (tid < nr) wl[tid] = w[base + i0 + tid];
  __syncthreads();
  float a0 = 0.f, a1 = 0.f;
  const unsigned short* mp = midb + (base + i0) * MDIM + 2 * tid;
  int i = 0;
  for (; i + 2 <= nr; i += 2){
    unsigned pk0 = *(const unsigned*)(mp + (size_t)i * MDIM);
    unsigned pk1 = *(const unsigned*)(mp + (size_t)(i + 1) * MDIM);
    float w0 = wl[i], w1 = wl[i + 1];
    a0 += w0 * bf2f((unsigned short)(pk0 & 0xffff)) + w1 * bf2f((unsigned short)(pk1 & 0xffff));
    a1 += w0 * bf2f((unsigned short)(pk0 >> 16)) + w1 * bf2f((unsigned short)(pk1 >> 16));
  }
  if (i < nr){
    unsigned pk0 = *(const unsigned*)(mp + (size_t)i * MDIM);
    float w0 = wl[i];
    a0 += w0 * bf2f((unsigned short)(pk0 & 0xffff));
    a1 += w0 * bf2f((unsigned short)(pk0 >> 16));
  }
  float* dst = bagp + (size_t)blockIdx.x * MDIM + 2 * tid;
  dst[0] = a0; dst[1] = a1;
}

// ---------------- final: exact re-rank, preds, feature copy — FLOAT32 output ----------------
__global__ __launch_bounds__(256) void kfinal(const float* __restrict__ bagp,
                                              const float* __restrict__ Wc,
                                              const float* __restrict__ bc,
                                              const float* __restrict__ emid,
                                              const float* __restrict__ ekey,
                                              const int* __restrict__ cand,
                                              float* __restrict__ out){
  __shared__ float k32[32];
  __shared__ int s32[32];
  __shared__ int ordv[32];
  __shared__ float r0[256], r1[256];
  int g = blockIdx.x, tid = threadIdx.x;
  if (tid < 32){ k32[tid] = ekey[g * 32 + tid]; s32[tid] = cand[g * 32 + tid]; }
  __syncthreads();
  if (tid == 0){
    unsigned used = 0;
    for (int a = 0; a < 32; a++){
      int best = -1;
      for (int b = 0; b < 32; b++){
        if ((used >> b) & 1u) continue;
        if (best < 0 || k32[b] > k32[best] || (k32[b] == k32[best] && s32[b] < s32[best])) best = b;
      }
      used |= 1u << best;
      ordv[a] = best;
    }
  }
  float p0 = 0.f, p1 = 0.f;
  for (int j = tid; j < 512; j += 256){
    float bv = 0.f;
    for (int s2 = 0; s2 < 128; s2++) bv += bagp[(size_t)(g * 128 + s2) * MDIM + j];
    p0 += bv * Wc[j];
    p1 += bv * Wc[512 + j];
  }
  r0[tid] = p0; r1[tid] = p1; __syncthreads();
  for (int s = 128; s > 0; s >>= 1){ if (tid < s){ r0[tid] += r0[tid + s]; r1[tid] += r1[tid + s]; } __syncthreads(); }
  if (tid == 0){
    out[g * 2 + 0] = r0[0] + bc[0];
    out[g * 2 + 1] = r1[0] + bc[1];
  }
  __syncthreads();
  for (int p = 0; p < 8; p++){
    int cc = ordv[p < 4 ? p : 24 + p];
    const float* src = emid + (size_t)(g * 32 + cc) * MDIM;
    float* dst = out + 16 + (size_t)(g * 8 + p) * MDIM;
    for (int j = tid; j < 512; j += 256) dst[j] = src[j];
  }
}

extern "C" void kernel_launch(void* const* d_in, const int* in_sizes, int n_in,
                              void* d_out, int out_size, void* d_ws, size_t ws_size,
                              hipStream_t stream){
  const int*   idxf = (const int*)d_in[0];
  const float* tfeat= (const float*)d_in[1];
  const float* W1   = (const float*)d_in[2];
  const float* b1   = (const float*)d_in[3];
  const float* Wa1  = (const float*)d_in[4];
  const float* ba1  = (const float*)d_in[5];
  const float* Wa2  = (const float*)d_in[6];
  const float* ba2  = (const float*)d_in[7];
  const float* Wc   = (const float*)d_in[8];
  const float* bc   = (const float*)d_in[9];
  float* out = (float*)d_out;
  (void)in_sizes; (void)n_in; (void)out_size; (void)ws_size;

  char* ws = (char*)d_ws;
  size_t off = 0;
  auto alloc = [&](size_t bytes){ void* p = ws + off; off += (bytes + 255) & ~(size_t)255; return p; };
  float* lv    = (float*)alloc((size_t)N_TOT * 4);
  float* tv    = (float*)alloc((size_t)N_TOT * 4);   // reused as w inside kselect
  float* maxlw = (float*)alloc(NUM_GROUP * 4);
  float* Zw    = (float*)alloc(NUM_GROUP * 4);
  int*   cand  = (int*)alloc(NUM_GROUP * 32 * 4);
  float* ekey  = (float*)alloc(NUM_GROUP * 32 * 4);
  float* emid  = (float*)alloc((size_t)NUM_GROUP * 32 * MDIM * 4);
  float* bagp  = (float*)alloc((size_t)NUM_GROUP * 128 * MDIM * 4);
  unsigned short* W1b  = (unsigned short*)alloc((size_t)MDIM * IN_CHN * 2);
  unsigned short* Wa1b = (unsigned short*)alloc((size_t)ATT_D * MDIM * 2);
  unsigned short* midb = (unsigned short*)alloc((size_t)N_TOT * MDIM * 2);
  float* w = tv;  // tv fully consumed inside kselect before w is written

  kconv<<<2304, 256, 0, stream>>>(W1, Wa1, W1b, Wa1b);
  kgemm_mid<<<3128, 256, 0, stream>>>(idxf, tfeat, W1b, b1, midb);
  kattn<<<782, 256, 0, stream>>>(midb, Wa1b, ba1, Wa2, ba2, Wc, lv, tv);
  kselect<<<8, 256, 0, stream>>>(lv, tv, maxlw, Zw, cand, w);
  kexact<<<256, 256, 0, stream>>>(idxf, tfeat, W1, b1, Wa1, ba1, Wa2, ba2, Wc, cand, maxlw, emid, ekey);
  kbag<<<1024, 256, 0, stream>>>(midb, w, bagp);
  kfinal<<<8, 256, 0, stream>>>(bagp, Wc, bc, emid, ekey, cand, out);
}